// Round 1
// baseline (586.178 us; speedup 1.0000x reference)
//
#include <hip/hip_runtime.h>
#include <math.h>

#define NG    256          // graphs
#define D     128          // feature dim
#define EPG   4096         // edge capacity per graph (constant across stages)
#define NEDGE (NG*EPG)     // 1048576
#define CAP   64           // incoming-edge bucket capacity per node
#define N1    65536        // stage-1 node count

// ---------------------------------------------------------------------------
// Pass 1 per stage: degrees + incoming-edge buckets in a single atomic pass.
// cnt_in's atomicAdd return value doubles as the bucket slot.
__global__ __launch_bounds__(256) void k_build(
    const int* __restrict__ src, const int* __restrict__ dst,
    int* __restrict__ cnt_in, int* __restrict__ cnt_out, int* __restrict__ bucket)
{
    int e = blockIdx.x * 256 + threadIdx.x;
    int s = src[e];
    if (s < 0) return;                 // masked-out edge (stages 2/3)
    int d = dst[e];
    atomicAdd(&cnt_out[s], 1);
    int pos = atomicAdd(&cnt_in[d], 1);
    if (pos < CAP) bucket[(size_t)d * CAP + pos] = s;
}

// ---------------------------------------------------------------------------
// agg[n] = rsqrt(max(deg_in,1)) * sum_{incoming e} x[src_e] * rsqrt(max(deg_out[src_e],1))
// one 128-thread block per node; coalesced 512B row reads, L2-resident per graph.
__global__ __launch_bounds__(128) void k_aggregate(
    const float* __restrict__ x, const int* __restrict__ bucket,
    const int* __restrict__ cnt_in, const int* __restrict__ cnt_out,
    float* __restrict__ agg)
{
    int n = blockIdx.x, t = threadIdx.x;
    int cnt = cnt_in[n]; if (cnt > CAP) cnt = CAP;
    const int* bk = bucket + (size_t)n * CAP;
    float acc = 0.f;
    int i = 0;
    for (; i + 2 <= cnt; i += 2) {        // 2-way unroll for ILP
        int s0 = bk[i], s1 = bk[i + 1];
        float v0 = x[(size_t)s0 * D + t] * rsqrtf((float)max(cnt_out[s0], 1));
        float v1 = x[(size_t)s1 * D + t] * rsqrtf((float)max(cnt_out[s1], 1));
        acc += v0; acc += v1;
    }
    if (i < cnt) {
        int s0 = bk[i];
        acc += x[(size_t)s0 * D + t] * rsqrtf((float)max(cnt_out[s0], 1));
    }
    agg[(size_t)n * D + t] = acc * rsqrtf((float)max(cnt, 1));
}

// ---------------------------------------------------------------------------
// out = res + relu(agg @ W + b); epilogue also emits t[n] = dot(out[n],Ws)*rsqrt(deg_out[n]).
// Tile 128x128, 256 threads, 8x8 micro-tile. Both operands staged in LDS as float4
// arrays, stride 33 (odd mod 8) with even/odd row de-interleave so per-instruction
// bank-quads spread across all 8 -> <=2-way conflicts. 4 K-phases, 42KB LDS.
__global__ __launch_bounds__(256) void k_gemm(
    const float* __restrict__ A, const float* __restrict__ Wm,
    const float* __restrict__ bias, const float* __restrict__ res,
    const float* __restrict__ Wsv, const int* __restrict__ cnt_out,
    float* __restrict__ outp, float* __restrict__ tbuf)
{
    __shared__ float4 At4[32 * 33];   // [perm(r/4)][kl]  rows of A (transposed)
    __shared__ float4 Wt4[32 * 33];   // [perm(c/4)][kl]
    __shared__ float  Wsl[128];
    __shared__ float  part[128 * 17];
    const int t  = threadIdx.x;
    const int tr = t >> 4;            // 0..15 : rows 8tr..8tr+7
    const int tc = t & 15;            // 0..15 : cols 8tc..8tc+7
    const int cb = tc * 8;
    const size_t r0 = (size_t)blockIdx.x * 128;

    if (t < 128) Wsl[t] = Wsv[t];

    float acc[8][8];
#pragma unroll
    for (int i = 0; i < 8; ++i)
#pragma unroll
        for (int j = 0; j < 8; ++j) acc[i][j] = 0.f;

    for (int ph = 0; ph < 4; ++ph) {
        __syncthreads();
        // stage A-quarter: 128 rows x 32 k  (1024 float4, coalesced reads)
#pragma unroll
        for (int s2 = 0; s2 < 4; ++s2) {
            int idx = t + 256 * s2;
            int r  = idx >> 3;        // 0..127
            int kc = idx & 7;         // 0..7
            float4 v = *(const float4*)&A[(r0 + r) * D + ph * 32 + kc * 4];
            int r4 = r >> 2, lane = r & 3;
            int prow = (r4 >> 1) | ((r4 & 1) << 4);
            float* base = (float*)&At4[prow * 33 + kc * 4];
            base[0  + lane] = v.x;
            base[4  + lane] = v.y;
            base[8  + lane] = v.z;
            base[12 + lane] = v.w;
        }
        // stage W-quarter: 32 k x 128 cols
#pragma unroll
        for (int s2 = 0; s2 < 4; ++s2) {
            int idx = t + 256 * s2;
            int wr  = idx >> 5;       // 0..31 (k)
            int wc4 = idx & 31;       // col quad
            float4 v = *(const float4*)&Wm[(size_t)(ph * 32 + wr) * D + wc4 * 4];
            int pcol = (wc4 >> 1) | ((wc4 & 1) << 4);
            Wt4[pcol * 33 + wr] = v;
        }
        __syncthreads();
#pragma unroll 4
        for (int kl = 0; kl < 32; ++kl) {
            float4 a0 = At4[tr * 33 + kl];          // rows 8tr..8tr+3
            float4 a1 = At4[(tr + 16) * 33 + kl];   // rows 8tr+4..8tr+7
            float4 w0 = Wt4[tc * 33 + kl];
            float4 w1 = Wt4[(tc + 16) * 33 + kl];
            float av[8] = {a0.x, a0.y, a0.z, a0.w, a1.x, a1.y, a1.z, a1.w};
            float wv[8] = {w0.x, w0.y, w0.z, w0.w, w1.x, w1.y, w1.z, w1.w};
#pragma unroll
            for (int i = 0; i < 8; ++i)
#pragma unroll
                for (int j = 0; j < 8; ++j)
                    acc[i][j] += av[i] * wv[j];
        }
    }
    __syncthreads();
    float bv[8];
#pragma unroll
    for (int j = 0; j < 8; ++j) bv[j] = bias[cb + j];
#pragma unroll
    for (int i = 0; i < 8; ++i) {
        size_t row = r0 + tr * 8 + i;
        float4 rA = *(const float4*)&res[row * D + cb];
        float4 rB = *(const float4*)&res[row * D + cb + 4];
        float o0 = rA.x + fmaxf(acc[i][0] + bv[0], 0.f);
        float o1 = rA.y + fmaxf(acc[i][1] + bv[1], 0.f);
        float o2 = rA.z + fmaxf(acc[i][2] + bv[2], 0.f);
        float o3 = rA.w + fmaxf(acc[i][3] + bv[3], 0.f);
        float o4 = rB.x + fmaxf(acc[i][4] + bv[4], 0.f);
        float o5 = rB.y + fmaxf(acc[i][5] + bv[5], 0.f);
        float o6 = rB.z + fmaxf(acc[i][6] + bv[6], 0.f);
        float o7 = rB.w + fmaxf(acc[i][7] + bv[7], 0.f);
        *(float4*)&outp[row * D + cb]     = make_float4(o0, o1, o2, o3);
        *(float4*)&outp[row * D + cb + 4] = make_float4(o4, o5, o6, o7);
        float p = o0 * Wsl[cb + 0] + o1 * Wsl[cb + 1] + o2 * Wsl[cb + 2] + o3 * Wsl[cb + 3]
                + o4 * Wsl[cb + 4] + o5 * Wsl[cb + 5] + o6 * Wsl[cb + 6] + o7 * Wsl[cb + 7];
        part[(tr * 8 + i) * 17 + tc] = p;
    }
    __syncthreads();
    if (t < 128) {
        float s = 0.f;
#pragma unroll
        for (int j = 0; j < 16; ++j) s += part[t * 17 + j];
        size_t n = r0 + t;
        tbuf[n] = s * rsqrtf((float)max(cnt_out[n], 1));
    }
}

// ---------------------------------------------------------------------------
// Per-graph: pool score (scalar pushed-through GraphConv), tanh gate, exact
// lax.top_k selection via rank counting, dis/com permutations, new-id table,
// and (for stages 1-2) edge remapping for the induced subgraph.
template<int NPn, int K, bool REMAP>
__global__ __launch_bounds__(NPn) void k_pool(
    const float* __restrict__ tbuf, const int* __restrict__ bucket,
    const int* __restrict__ cnt_in, const float* __restrict__ bsv,
    const int* __restrict__ srcE, const int* __restrict__ dstE,
    float* __restrict__ score_out, float* __restrict__ gate_out,
    int* __restrict__ perm_dis, int* __restrict__ perm_com,
    int* __restrict__ src_next, int* __restrict__ dst_next)
{
    __shared__ float sc[NPn];
    __shared__ int   pf[NPn];
    __shared__ int   lid[NPn];
    const int g = blockIdx.x, t = threadIdx.x;
    const int n = g * NPn + t;

    int cnt = cnt_in[n]; if (cnt > CAP) cnt = CAP;
    const int* bk = bucket + (size_t)n * CAP;
    float a = 0.f;
    int i = 0;
    for (; i + 2 <= cnt; i += 2) { float v0 = tbuf[bk[i]]; float v1 = tbuf[bk[i + 1]]; a += v0; a += v1; }
    if (i < cnt) a += tbuf[bk[i]];
    float my = a * rsqrtf((float)max(cnt, 1)) + bsv[0];
    score_out[n] = my;
    gate_out[n]  = tanhf(my);
    sc[t] = my;
    __syncthreads();

    int rank = 0;
    for (int j = 0; j < NPn; ++j) {
        float v = sc[j];
        rank += (int)((v > my) || (v == my && j < t));
    }
    const int kept = (rank < K) ? 1 : 0;
    pf[t] = kept;
    __syncthreads();
    int val = kept;
    for (int off = 1; off < NPn; off <<= 1) {
        int add = (t >= off) ? pf[t - off] : 0;
        __syncthreads();
        val += add;
        pf[t] = val;
        __syncthreads();
    }
    int excl = val - kept;                       // kept nodes before me (ascending ids)
    if (kept) { lid[t] = excl;  perm_dis[g * K + excl] = n; }
    else      { lid[t] = -1;    perm_com[g * (NPn - K) + (t - excl)] = n; }
    __syncthreads();

    if (REMAP) {
        for (int e = g * EPG + t; e < (g + 1) * EPG; e += NPn) {
            int s = srcE[e];
            int ns = -1, nd = -1;
            if (s >= 0) {
                int ls  = lid[s - g * NPn];
                int ld2 = lid[dstE[e] - g * NPn];
                if (ls >= 0 && ld2 >= 0) { ns = g * K + ls; nd = g * K + ld2; }
            }
            src_next[e] = ns;
            dst_next[e] = nd;
        }
    }
}

// ---------------------------------------------------------------------------
__global__ __launch_bounds__(128) void k_gather(
    const float* __restrict__ x, const float* __restrict__ gate,
    const int* __restrict__ perm, float* __restrict__ outf)
{
    int i = blockIdx.x, t = threadIdx.x;
    int old = perm[i];
    outf[(size_t)i * D + t] = x[(size_t)old * D + t] * gate[old];
}

// readout (mean || max) for dis (blocks 0..255 -> hg+=) and com (blocks 256..511 -> hg_com+=,
// optional copy for the hg3_com output). Gated features gathered on the fly.
__global__ __launch_bounds__(128) void k_readout(
    const float* __restrict__ x, const float* __restrict__ gate,
    const int* __restrict__ perm_dis, const int* __restrict__ perm_com,
    int kcnt, float* __restrict__ hg, float* __restrict__ hgc,
    float* __restrict__ copy_com)
{
    int b = blockIdx.x, t = threadIdx.x;
    int com = (b >= NG) ? 1 : 0;
    int g = com ? b - NG : b;
    const int* perm = (com ? perm_com : perm_dis) + (size_t)g * kcnt;
    float sm = 0.f, mx = -INFINITY;
    for (int r = 0; r < kcnt; ++r) {
        int old = perm[r];
        float v = x[(size_t)old * D + t] * gate[old];
        sm += v;
        mx = fmaxf(mx, v);
    }
    float mean = sm * (1.f / (float)kcnt);
    float* dstp = com ? hgc : hg;
    dstp[(size_t)g * 256 + t]       += mean;
    dstp[(size_t)g * 256 + 128 + t] += mx;
    if (com && copy_com) {
        copy_com[(size_t)g * 256 + t]       = mean;
        copy_com[(size_t)g * 256 + 128 + t] = mx;
    }
}

// ---------------------------------------------------------------------------
// node_pred = mlp(out3): 16 rows per block, weights in LDS.
__global__ __launch_bounds__(256) void k_node_mlp(
    const float* __restrict__ X,
    const float* __restrict__ W0, const float* __restrict__ b0,
    const float* __restrict__ W1, const float* __restrict__ b1,
    const float* __restrict__ W2, const float* __restrict__ b2,
    float* __restrict__ outp)
{
    __shared__ float xs[16 * 132];
    __shared__ float w0[128 * 64];
    __shared__ float h0[16 * 65];
    __shared__ float w1[64 * 32];
    __shared__ float h1[16 * 33];
    __shared__ float w2[32 * 10];
    int t = threadIdx.x;
    int r0 = blockIdx.x * 16;
    for (int i = t; i < 128 * 64; i += 256) w0[i] = W0[i];
    for (int i = t; i < 64 * 32;  i += 256) w1[i] = W1[i];
    for (int i = t; i < 320;      i += 256) w2[i] = W2[i];
    for (int i = t; i < 16 * 128; i += 256)
        xs[(i >> 7) * 132 + (i & 127)] = X[(size_t)(r0 + (i >> 7)) * D + (i & 127)];
    __syncthreads();
    {   // L0: 128 -> 64, relu
        int r = t >> 4, c = (t & 15) * 4;
        float a0 = b0[c], a1 = b0[c + 1], a2 = b0[c + 2], a3 = b0[c + 3];
        const float* xr = &xs[r * 132];
        for (int k = 0; k < 128; ++k) {
            float xv = xr[k];
            float4 w = *(const float4*)&w0[k * 64 + c];
            a0 += xv * w.x; a1 += xv * w.y; a2 += xv * w.z; a3 += xv * w.w;
        }
        float* hr = &h0[r * 65 + c];
        hr[0] = fmaxf(a0, 0.f); hr[1] = fmaxf(a1, 0.f); hr[2] = fmaxf(a2, 0.f); hr[3] = fmaxf(a3, 0.f);
    }
    __syncthreads();
    {   // L1: 64 -> 32, relu
        int r = t >> 4, c = (t & 15) * 2;
        float a0 = b1[c], a1 = b1[c + 1];
        const float* hr = &h0[r * 65];
        for (int k = 0; k < 64; ++k) {
            float xv = hr[k];
            a0 += xv * w1[k * 32 + c];
            a1 += xv * w1[k * 32 + c + 1];
        }
        h1[r * 33 + c]     = fmaxf(a0, 0.f);
        h1[r * 33 + c + 1] = fmaxf(a1, 0.f);
    }
    __syncthreads();
    if (t < 160) {  // L2: 32 -> 10
        int r = t / 10, c = t % 10;
        float a = b2[c];
        const float* hr = &h1[r * 33];
        for (int k = 0; k < 32; ++k) a += hr[k] * w2[k * 10 + c];
        outp[(size_t)(r0 + r) * 10 + c] = a;
    }
}

// scores (rows 0..255 from hg) and scores_com (rows 256..511 from hg_com) in one kernel;
// outputs are adjacent in d_out. 32 rows per block, 16 blocks.
__global__ __launch_bounds__(256) void k_graph_mlp(
    const float* __restrict__ hg, const float* __restrict__ hgc,
    const float* __restrict__ Wg0, const float* __restrict__ bg0,
    const float* __restrict__ Wg1, const float* __restrict__ bg1,
    const float* __restrict__ Wg2, const float* __restrict__ bg2,
    float* __restrict__ outp)
{
    __shared__ float xs[32 * 257];
    __shared__ float h0[32 * 129];
    __shared__ float h1[32 * 65];
    int t = threadIdx.x;
    int row0 = blockIdx.x * 32;
    for (int i = t; i < 32 * 256; i += 256) {
        int r = row0 + (i >> 8);
        float v = (r < NG) ? hg[(size_t)r * 256 + (i & 255)]
                           : hgc[(size_t)(r - NG) * 256 + (i & 255)];
        xs[(i >> 8) * 257 + (i & 255)] = v;
    }
    __syncthreads();
    {   // L0: 256 -> 128, relu; thread owns col c for 16 rows
        int c = t & 127, rh = (t >> 7) * 16;
        float acc[16];
        float bb = bg0[c];
#pragma unroll
        for (int r = 0; r < 16; ++r) acc[r] = bb;
        for (int k = 0; k < 256; ++k) {
            float w = Wg0[(size_t)k * 128 + c];
#pragma unroll
            for (int r = 0; r < 16; ++r) acc[r] += xs[(rh + r) * 257 + k] * w;
        }
#pragma unroll
        for (int r = 0; r < 16; ++r) h0[(rh + r) * 129 + c] = fmaxf(acc[r], 0.f);
    }
    __syncthreads();
    {   // L1: 128 -> 64, relu
        int c = t & 63, rq = (t >> 6) * 8;
        float acc[8];
        float bb = bg1[c];
#pragma unroll
        for (int r = 0; r < 8; ++r) acc[r] = bb;
        for (int k = 0; k < 128; ++k) {
            float w = Wg1[(size_t)k * 64 + c];
#pragma unroll
            for (int r = 0; r < 8; ++r) acc[r] += h0[(rq + r) * 129 + k] * w;
        }
#pragma unroll
        for (int r = 0; r < 8; ++r) h1[(rq + r) * 65 + c] = fmaxf(acc[r], 0.f);
    }
    __syncthreads();
    for (int idx = t; idx < 320; idx += 256) {  // L2: 64 -> 10
        int r = idx / 10, c = idx % 10;
        float a = bg2[c];
        for (int k = 0; k < 64; ++k) a += h1[r * 65 + k] * Wg2[k * 10 + c];
        outp[(size_t)(row0 + r) * 10 + c] = a;
    }
}

// ---------------------------------------------------------------------------
// node_score1 = softmax over the whole 65536-element stage-1 score vector.
__global__ __launch_bounds__(256) void k_smax_part(const float* __restrict__ sc, float* __restrict__ pmax) {
    __shared__ float red[256];
    int t = threadIdx.x;
    float m = -INFINITY;
    for (int i = blockIdx.x * 256 + t; i < N1; i += 64 * 256) m = fmaxf(m, sc[i]);
    red[t] = m; __syncthreads();
    for (int off = 128; off > 0; off >>= 1) {
        if (t < off) red[t] = fmaxf(red[t], red[t + off]);
        __syncthreads();
    }
    if (t == 0) pmax[blockIdx.x] = red[0];
}
__global__ __launch_bounds__(256) void k_smax_sum(const float* __restrict__ sc, const float* __restrict__ pmax,
                                                 float* __restrict__ psum) {
    __shared__ float red[256];
    int t = threadIdx.x;
    float gm = -INFINITY;
#pragma unroll
    for (int i = 0; i < 64; ++i) gm = fmaxf(gm, pmax[i]);
    float s = 0.f;
    for (int i = blockIdx.x * 256 + t; i < N1; i += 64 * 256) s += expf(sc[i] - gm);
    red[t] = s; __syncthreads();
    for (int off = 128; off > 0; off >>= 1) {
        if (t < off) red[t] += red[t + off];
        __syncthreads();
    }
    if (t == 0) psum[blockIdx.x] = red[0];
}
__global__ __launch_bounds__(256) void k_smax_out(const float* __restrict__ sc, const float* __restrict__ pmax,
                                                 const float* __restrict__ psum, float* __restrict__ outp) {
    int t = threadIdx.x;
    float gm = -INFINITY; float gs = 0.f;
#pragma unroll
    for (int i = 0; i < 64; ++i) { gm = fmaxf(gm, pmax[i]); gs += psum[i]; }
    int i = blockIdx.x * 256 + t;
    outp[i] = expf(sc[i] - gm) / gs;
}

// ---------------------------------------------------------------------------
extern "C" void kernel_launch(void* const* d_in, const int* in_sizes, int n_in,
                              void* d_out, int out_size, void* d_ws, size_t ws_size,
                              hipStream_t stream) {
    const float* feature = (const float*)d_in[0];
    const int*   src     = (const int*)d_in[1];
    const int*   dst     = (const int*)d_in[2];
    // d_in[3] = label (unused by reference)
    const float* W1  = (const float*)d_in[4];
    const float* b1  = (const float*)d_in[5];
    const float* W2  = (const float*)d_in[6];
    const float* b2  = (const float*)d_in[7];
    const float* W3  = (const float*)d_in[8];
    const float* b3  = (const float*)d_in[9];
    const float* Wsv = (const float*)d_in[10];
    const float* bsv = (const float*)d_in[11];
    const float* Wg0 = (const float*)d_in[12];
    const float* bg0 = (const float*)d_in[13];
    const float* Wg1 = (const float*)d_in[14];
    const float* bg1 = (const float*)d_in[15];
    const float* Wg2 = (const float*)d_in[16];
    const float* bg2 = (const float*)d_in[17];
    const float* Wp0 = (const float*)d_in[18];
    const float* bp0 = (const float*)d_in[19];
    const float* Wp1 = (const float*)d_in[20];
    const float* bp1 = (const float*)d_in[21];
    const float* Wp2 = (const float*)d_in[22];
    const float* bp2 = (const float*)d_in[23];

    float* out = (float*)d_out;
    float* o_scores    = out;            // [512][10] = scores || scores_com
    float* o_hg3com    = out + 5120;     // [256][256]
    float* o_nodepred  = out + 70656;    // [16384][10]
    float* o_nodescore = out + 234496;   // [65536]

    // ---- carve workspace (all offsets multiples of 64 floats) -------------
    float* ws = (float*)d_ws;
    size_t off = 0;
    auto alloc_f = [&](size_t n) { float* p = ws + off; off += (n + 63) & ~(size_t)63; return p; };
    float* agg    = alloc_f(8388608);   // [65536][128]
    float* outbuf = alloc_f(8388608);   // out1 -> out2 -> out3
    float* f1d    = alloc_f(4194304);   // [32768][128]
    float* f2d    = alloc_f(2097152);   // [16384][128]
    int*   bucket = (int*)alloc_f(4194304);   // [65536][64]
    int*   src2   = (int*)alloc_f(1048576);
    int*   dst2   = (int*)alloc_f(1048576);
    int*   src3   = (int*)alloc_f(1048576);
    int*   dst3   = (int*)alloc_f(1048576);
    int*   cnt_in = (int*)alloc_f(65536);     // cnt_in & cnt_out contiguous (one memset)
    int*   cnt_out= (int*)alloc_f(65536);
    float* tbuf   = alloc_f(65536);
    float* gate   = alloc_f(65536);
    float* score1 = alloc_f(65536);
    float* scoreX = alloc_f(65536);
    int*   perm_d = (int*)alloc_f(32768);
    int*   perm_c = (int*)alloc_f(32768);
    float* hg     = alloc_f(65536);           // hg & hg_com contiguous (one memset)
    float* hg_com = alloc_f(65536);
    float* pmax   = alloc_f(64);
    float* psum   = alloc_f(64);
    (void)ws_size; (void)in_sizes; (void)n_in; (void)out_size;

    hipMemsetAsync(hg, 0, 2 * 65536 * sizeof(float), stream);

    // =================== stage 1 (N=65536, np=256, k=128) ==================
    hipMemsetAsync(cnt_in, 0, 2 * 65536 * sizeof(int), stream);
    k_build<<<NEDGE / 256, 256, 0, stream>>>(src, dst, cnt_in, cnt_out, bucket);
    k_aggregate<<<65536, 128, 0, stream>>>(feature, bucket, cnt_in, cnt_out, agg);
    k_gemm<<<65536 / 128, 256, 0, stream>>>(agg, W1, b1, feature, Wsv, cnt_out, outbuf, tbuf);
    k_pool<256, 128, true><<<NG, 256, 0, stream>>>(tbuf, bucket, cnt_in, bsv, src, dst,
                                                   score1, gate, perm_d, perm_c, src2, dst2);
    k_gather<<<NG * 128, 128, 0, stream>>>(outbuf, gate, perm_d, f1d);
    k_readout<<<2 * NG, 128, 0, stream>>>(outbuf, gate, perm_d, perm_c, 128, hg, hg_com, nullptr);

    // =================== stage 2 (N=32768, np=128, k=64) ===================
    hipMemsetAsync(cnt_in, 0, 2 * 65536 * sizeof(int), stream);
    k_build<<<NEDGE / 256, 256, 0, stream>>>(src2, dst2, cnt_in, cnt_out, bucket);
    k_aggregate<<<32768, 128, 0, stream>>>(f1d, bucket, cnt_in, cnt_out, agg);
    k_gemm<<<32768 / 128, 256, 0, stream>>>(agg, W2, b2, f1d, Wsv, cnt_out, outbuf, tbuf);
    k_pool<128, 64, true><<<NG, 128, 0, stream>>>(tbuf, bucket, cnt_in, bsv, src2, dst2,
                                                  scoreX, gate, perm_d, perm_c, src3, dst3);
    k_gather<<<NG * 64, 128, 0, stream>>>(outbuf, gate, perm_d, f2d);
    k_readout<<<2 * NG, 128, 0, stream>>>(outbuf, gate, perm_d, perm_c, 64, hg, hg_com, nullptr);

    // =================== stage 3 (N=16384, np=64, k=32) ====================
    hipMemsetAsync(cnt_in, 0, 2 * 65536 * sizeof(int), stream);
    k_build<<<NEDGE / 256, 256, 0, stream>>>(src3, dst3, cnt_in, cnt_out, bucket);
    k_aggregate<<<16384, 128, 0, stream>>>(f2d, bucket, cnt_in, cnt_out, agg);
    k_gemm<<<16384 / 128, 256, 0, stream>>>(agg, W3, b3, f2d, Wsv, cnt_out, outbuf, tbuf);
    k_pool<64, 32, false><<<NG, 64, 0, stream>>>(tbuf, bucket, cnt_in, bsv, nullptr, nullptr,
                                                 scoreX, gate, perm_d, perm_c, nullptr, nullptr);
    k_readout<<<2 * NG, 128, 0, stream>>>(outbuf, gate, perm_d, perm_c, 32, hg, hg_com, o_hg3com);

    // =================== heads =============================================
    k_node_mlp<<<16384 / 16, 256, 0, stream>>>(outbuf, Wp0, bp0, Wp1, bp1, Wp2, bp2, o_nodepred);
    k_graph_mlp<<<16, 256, 0, stream>>>(hg, hg_com, Wg0, bg0, Wg1, bg1, Wg2, bg2, o_scores);
    k_smax_part<<<64, 256, 0, stream>>>(score1, pmax);
    k_smax_sum<<<64, 256, 0, stream>>>(score1, pmax, psum);
    k_smax_out<<<N1 / 256, 256, 0, stream>>>(score1, pmax, psum, o_nodescore);
}

// Round 5
// 583.932 us; speedup vs baseline: 1.0038x; 1.0038x over previous
//
#include <hip/hip_runtime.h>
#include <math.h>

#define NG    256          // graphs
#define D     128          // feature dim
#define EPG   4096         // edge capacity per graph (constant across stages)
#define NEDGE (NG*EPG)     // 1048576
#define CAP   64           // incoming-edge bucket capacity per node
#define N1    65536        // stage-1 node count

typedef unsigned short u16;

// ---------------------------------------------------------------------------
// Pass 1 per stage: degrees + incoming-edge buckets (ushort LOCAL ids) in one
// atomic pass. Block swizzle keeps each graph's cnt/bucket region on one XCD
// (graph g -> XCD g/32, consistent with k_agg_g / k_pool / k_gemm below).
__global__ __launch_bounds__(256) void k_build(
    const int* __restrict__ src, const int* __restrict__ dst,
    int* __restrict__ cnt_in, int* __restrict__ cnt_out,
    u16* __restrict__ bucket, int npmask)
{
    int lb = ((blockIdx.x & 7) << 9) | (blockIdx.x >> 3);   // 4096 blocks, chunk 512
    int e = lb * 256 + threadIdx.x;
    int s = src[e];
    if (s < 0) return;                 // masked-out edge (stages 2/3)
    int d = dst[e];
    atomicAdd(&cnt_out[s], 1);
    int pos = atomicAdd(&cnt_in[d], 1);
    if (pos < CAP) bucket[(size_t)d * CAP + pos] = (u16)(s & npmask);
}

// ---------------------------------------------------------------------------
// Graph-centric aggregation: one block per graph, features staged in LDS
// (pre-scaled by rsqrt(deg_out)), per-wave node gather via readlane broadcast
// + conflict-free ds_read_b64 (full 512B row per instruction).
template<int NPn>
__global__ __launch_bounds__(512) void k_agg_g(
    const float* __restrict__ x, const u16* __restrict__ bucket,
    const int* __restrict__ cnt_in, const int* __restrict__ cnt_out,
    float* __restrict__ agg)
{
    __shared__ float feat[NPn * 128];
    __shared__ float scl[NPn];
    __shared__ int   cl[NPn];
    const int g = ((blockIdx.x & 7) << 5) | (blockIdx.x >> 3);  // graph g on XCD g/32
    const int t = threadIdx.x;

    if (t < NPn) cl[t] = min(cnt_in[g * NPn + t], CAP);
    if (t >= 256 && t < 256 + NPn) {
        int r = t - 256;
        scl[r] = rsqrtf((float)max(cnt_out[g * NPn + r], 1));
    }
    __syncthreads();
    // stage features, scaled by rsqrt(deg_out)
    for (int idx = t; idx < NPn * 32; idx += 512) {
        int r = idx >> 5, q = idx & 31;
        float4 v = *(const float4*)&x[((size_t)(g * NPn + r)) * D + q * 4];
        float s = scl[r];
        v.x *= s; v.y *= s; v.z *= s; v.w *= s;
        *(float4*)&feat[r * 128 + q * 4] = v;
    }
    __syncthreads();

    const int w = t >> 6, l = t & 63;
    int n = w;
    int cnt = 0, bv = 0;
    if (n < NPn) {
        cnt = __builtin_amdgcn_readfirstlane(cl[n]);
        const u16* bk = bucket + (size_t)(g * NPn + n) * CAP;
        bv = (l < cnt) ? (int)bk[l] : 0;
    }
    while (n < NPn) {
        // prefetch next node's bucket row before the dependent inner loop
        int n2 = n + 8, cnt2 = 0, bv2 = 0;
        if (n2 < NPn) {
            cnt2 = __builtin_amdgcn_readfirstlane(cl[n2]);
            const u16* bk2 = bucket + (size_t)(g * NPn + n2) * CAP;
            bv2 = (l < cnt2) ? (int)bk2[l] : 0;
        }
        float ax = 0.f, ay = 0.f;
        int i = 0;
        for (; i + 2 <= cnt; i += 2) {
            int s0 = __builtin_amdgcn_readlane(bv, i);
            int s1 = __builtin_amdgcn_readlane(bv, i + 1);
            float2 v0 = *(const float2*)&feat[s0 * 128 + 2 * l];
            float2 v1 = *(const float2*)&feat[s1 * 128 + 2 * l];
            ax += v0.x; ay += v0.y; ax += v1.x; ay += v1.y;
        }
        if (i < cnt) {
            int s0 = __builtin_amdgcn_readlane(bv, i);
            float2 v0 = *(const float2*)&feat[s0 * 128 + 2 * l];
            ax += v0.x; ay += v0.y;
        }
        float sc = rsqrtf((float)max(cnt, 1));
        *(float2*)&agg[((size_t)(g * NPn + n)) * D + 2 * l] = make_float2(ax * sc, ay * sc);
        n = n2; cnt = cnt2; bv = bv2;
    }
}

// ---------------------------------------------------------------------------
// out = res + relu(agg @ W + b); epilogue also emits t[n] = dot(out[n],Ws)*rsqrt(deg_out).
__global__ __launch_bounds__(256) void k_gemm(
    const float* __restrict__ A, const float* __restrict__ Wm,
    const float* __restrict__ bias, const float* __restrict__ res,
    const float* __restrict__ Wsv, const int* __restrict__ cnt_out,
    float* __restrict__ outp, float* __restrict__ tbuf)
{
    __shared__ float4 At4[32 * 33];   // [perm(r/4)][kl]  rows of A (transposed)
    __shared__ float4 Wt4[32 * 33];   // [perm(c/4)][kl]
    __shared__ float  Wsl[128];
    __shared__ float  part[128 * 17];
    const int t  = threadIdx.x;
    const int tr = t >> 4;            // 0..15 : rows 8tr..8tr+7
    const int tc = t & 15;            // 0..15 : cols 8tc..8tc+7
    const int cb = tc * 8;
    const int lb = ((blockIdx.x & 7) * (gridDim.x >> 3)) + (blockIdx.x >> 3);
    const size_t r0 = (size_t)lb * 128;

    if (t < 128) Wsl[t] = Wsv[t];

    float acc[8][8];
#pragma unroll
    for (int i = 0; i < 8; ++i)
#pragma unroll
        for (int j = 0; j < 8; ++j) acc[i][j] = 0.f;

    for (int ph = 0; ph < 4; ++ph) {
        __syncthreads();
#pragma unroll
        for (int s2 = 0; s2 < 4; ++s2) {
            int idx = t + 256 * s2;
            int r  = idx >> 3;        // 0..127
            int kc = idx & 7;         // 0..7
            float4 v = *(const float4*)&A[(r0 + r) * D + ph * 32 + kc * 4];
            int r4 = r >> 2, lane = r & 3;
            int prow = (r4 >> 1) | ((r4 & 1) << 4);
            float* base = (float*)&At4[prow * 33 + kc * 4];
            base[0  + lane] = v.x;
            base[4  + lane] = v.y;
            base[8  + lane] = v.z;
            base[12 + lane] = v.w;
        }
#pragma unroll
        for (int s2 = 0; s2 < 4; ++s2) {
            int idx = t + 256 * s2;
            int wr  = idx >> 5;       // 0..31 (k)
            int wc4 = idx & 31;       // col quad
            float4 v = *(const float4*)&Wm[(size_t)(ph * 32 + wr) * D + wc4 * 4];
            int pcol = (wc4 >> 1) | ((wc4 & 1) << 4);
            Wt4[pcol * 33 + wr] = v;
        }
        __syncthreads();
#pragma unroll 4
        for (int kl = 0; kl < 32; ++kl) {
            float4 a0 = At4[tr * 33 + kl];
            float4 a1 = At4[(tr + 16) * 33 + kl];
            float4 w0 = Wt4[tc * 33 + kl];
            float4 w1 = Wt4[(tc + 16) * 33 + kl];
            float av[8] = {a0.x, a0.y, a0.z, a0.w, a1.x, a1.y, a1.z, a1.w};
            float wv[8] = {w0.x, w0.y, w0.z, w0.w, w1.x, w1.y, w1.z, w1.w};
#pragma unroll
            for (int i = 0; i < 8; ++i)
#pragma unroll
                for (int j = 0; j < 8; ++j)
                    acc[i][j] += av[i] * wv[j];
        }
    }
    __syncthreads();
    float bv[8];
#pragma unroll
    for (int j = 0; j < 8; ++j) bv[j] = bias[cb + j];
#pragma unroll
    for (int i = 0; i < 8; ++i) {
        size_t row = r0 + tr * 8 + i;
        float4 rA = *(const float4*)&res[row * D + cb];
        float4 rB = *(const float4*)&res[row * D + cb + 4];
        float o0 = rA.x + fmaxf(acc[i][0] + bv[0], 0.f);
        float o1 = rA.y + fmaxf(acc[i][1] + bv[1], 0.f);
        float o2 = rA.z + fmaxf(acc[i][2] + bv[2], 0.f);
        float o3 = rA.w + fmaxf(acc[i][3] + bv[3], 0.f);
        float o4 = rB.x + fmaxf(acc[i][4] + bv[4], 0.f);
        float o5 = rB.y + fmaxf(acc[i][5] + bv[5], 0.f);
        float o6 = rB.z + fmaxf(acc[i][6] + bv[6], 0.f);
        float o7 = rB.w + fmaxf(acc[i][7] + bv[7], 0.f);
        *(float4*)&outp[row * D + cb]     = make_float4(o0, o1, o2, o3);
        *(float4*)&outp[row * D + cb + 4] = make_float4(o4, o5, o6, o7);
        float p = o0 * Wsl[cb + 0] + o1 * Wsl[cb + 1] + o2 * Wsl[cb + 2] + o3 * Wsl[cb + 3]
                + o4 * Wsl[cb + 4] + o5 * Wsl[cb + 5] + o6 * Wsl[cb + 6] + o7 * Wsl[cb + 7];
        part[(tr * 8 + i) * 17 + tc] = p;
    }
    __syncthreads();
    if (t < 128) {
        float s = 0.f;
#pragma unroll
        for (int j = 0; j < 16; ++j) s += part[t * 17 + j];
        size_t n = r0 + t;
        tbuf[n] = s * rsqrtf((float)max(cnt_out[n], 1));
    }
}

// ---------------------------------------------------------------------------
// Per-graph pooling: score via pushed-through scalar GraphConv, exact top-k by
// rank counting, dis/com permutations, edge remap. Bucket entries are LOCAL ids.
template<int NPn, int K, bool REMAP>
__global__ __launch_bounds__(NPn) void k_pool(
    const float* __restrict__ tbuf, const u16* __restrict__ bucket,
    const int* __restrict__ cnt_in, const float* __restrict__ bsv,
    const int* __restrict__ srcE, const int* __restrict__ dstE,
    float* __restrict__ score_out, float* __restrict__ gate_out,
    int* __restrict__ perm_dis, int* __restrict__ perm_com,
    int* __restrict__ src_next, int* __restrict__ dst_next)
{
    __shared__ float sc[NPn];
    __shared__ int   pf[NPn];
    __shared__ int   lid[NPn];
    const int g = ((blockIdx.x & 7) << 5) | (blockIdx.x >> 3);
    const int t = threadIdx.x;
    const int n = g * NPn + t;

    int cnt = cnt_in[n]; if (cnt > CAP) cnt = CAP;
    const u16* bk = bucket + (size_t)n * CAP;
    float a = 0.f;
    int i = 0;
    for (; i + 2 <= cnt; i += 2) {
        float v0 = tbuf[g * NPn + bk[i]];
        float v1 = tbuf[g * NPn + bk[i + 1]];
        a += v0; a += v1;
    }
    if (i < cnt) a += tbuf[g * NPn + bk[i]];
    float my = a * rsqrtf((float)max(cnt, 1)) + bsv[0];
    score_out[n] = my;
    gate_out[n]  = tanhf(my);
    sc[t] = my;
    __syncthreads();

    int rank = 0;
    for (int j = 0; j < NPn; ++j) {
        float v = sc[j];
        rank += (int)((v > my) || (v == my && j < t));
    }
    const int kept = (rank < K) ? 1 : 0;
    pf[t] = kept;
    __syncthreads();
    int val = kept;
    for (int off = 1; off < NPn; off <<= 1) {
        int add = (t >= off) ? pf[t - off] : 0;
        __syncthreads();
        val += add;
        pf[t] = val;
        __syncthreads();
    }
    int excl = val - kept;
    if (kept) { lid[t] = excl;  perm_dis[g * K + excl] = n; }
    else      { lid[t] = -1;    perm_com[g * (NPn - K) + (t - excl)] = n; }
    __syncthreads();

    if (REMAP) {
        for (int e = g * EPG + t; e < (g + 1) * EPG; e += NPn) {
            int s = srcE[e];
            int ns = -1, nd = -1;
            if (s >= 0) {
                int ls  = lid[s - g * NPn];
                int ld2 = lid[dstE[e] - g * NPn];
                if (ls >= 0 && ld2 >= 0) { ns = g * K + ls; nd = g * K + ld2; }
            }
            src_next[e] = ns;
            dst_next[e] = nd;
        }
    }
}

// ---------------------------------------------------------------------------
__global__ __launch_bounds__(128) void k_gather(
    const float* __restrict__ x, const float* __restrict__ gate,
    const int* __restrict__ perm, float* __restrict__ outf)
{
    int i = blockIdx.x, t = threadIdx.x;
    int old = perm[i];
    outf[(size_t)i * D + t] = x[(size_t)old * D + t] * gate[old];
}

__global__ __launch_bounds__(128) void k_readout(
    const float* __restrict__ x, const float* __restrict__ gate,
    const int* __restrict__ perm_dis, const int* __restrict__ perm_com,
    int kcnt, float* __restrict__ hg, float* __restrict__ hgc,
    float* __restrict__ copy_com)
{
    int b = blockIdx.x, t = threadIdx.x;
    int com = (b >= NG) ? 1 : 0;
    int g = com ? b - NG : b;
    const int* perm = (com ? perm_com : perm_dis) + (size_t)g * kcnt;
    float sm = 0.f, mx = -INFINITY;
    int r = 0;
    for (; r + 4 <= kcnt; r += 4) {   // 4 rows in flight
        int o0 = perm[r], o1 = perm[r + 1], o2 = perm[r + 2], o3 = perm[r + 3];
        float v0 = x[(size_t)o0 * D + t] * gate[o0];
        float v1 = x[(size_t)o1 * D + t] * gate[o1];
        float v2 = x[(size_t)o2 * D + t] * gate[o2];
        float v3 = x[(size_t)o3 * D + t] * gate[o3];
        sm += v0; mx = fmaxf(mx, v0);
        sm += v1; mx = fmaxf(mx, v1);
        sm += v2; mx = fmaxf(mx, v2);
        sm += v3; mx = fmaxf(mx, v3);
    }
    for (; r < kcnt; ++r) {
        int o0 = perm[r];
        float v = x[(size_t)o0 * D + t] * gate[o0];
        sm += v; mx = fmaxf(mx, v);
    }
    float mean = sm * (1.f / (float)kcnt);
    float* dstp = com ? hgc : hg;
    dstp[(size_t)g * 256 + t]       += mean;
    dstp[(size_t)g * 256 + 128 + t] += mx;
    if (com && copy_com) {
        copy_com[(size_t)g * 256 + t]       = mean;
        copy_com[(size_t)g * 256 + 128 + t] = mx;
    }
}

// ---------------------------------------------------------------------------
__global__ __launch_bounds__(256) void k_node_mlp(
    const float* __restrict__ X,
    const float* __restrict__ W0, const float* __restrict__ b0,
    const float* __restrict__ W1, const float* __restrict__ b1,
    const float* __restrict__ W2, const float* __restrict__ b2,
    float* __restrict__ outp)
{
    __shared__ float xs[16 * 132];
    __shared__ float w0[128 * 64];
    __shared__ float h0[16 * 65];
    __shared__ float w1[64 * 32];
    __shared__ float h1[16 * 33];
    __shared__ float w2[32 * 10];
    int t = threadIdx.x;
    int r0 = blockIdx.x * 16;
    for (int i = t; i < 128 * 64; i += 256) w0[i] = W0[i];
    for (int i = t; i < 64 * 32;  i += 256) w1[i] = W1[i];
    for (int i = t; i < 320;      i += 256) w2[i] = W2[i];
    for (int i = t; i < 16 * 128; i += 256)
        xs[(i >> 7) * 132 + (i & 127)] = X[(size_t)(r0 + (i >> 7)) * D + (i & 127)];
    __syncthreads();
    {
        int r = t >> 4, c = (t & 15) * 4;
        float a0 = b0[c], a1 = b0[c + 1], a2 = b0[c + 2], a3 = b0[c + 3];
        const float* xr = &xs[r * 132];
        for (int k = 0; k < 128; ++k) {
            float xv = xr[k];
            float4 w = *(const float4*)&w0[k * 64 + c];
            a0 += xv * w.x; a1 += xv * w.y; a2 += xv * w.z; a3 += xv * w.w;
        }
        float* hr = &h0[r * 65 + c];
        hr[0] = fmaxf(a0, 0.f); hr[1] = fmaxf(a1, 0.f); hr[2] = fmaxf(a2, 0.f); hr[3] = fmaxf(a3, 0.f);
    }
    __syncthreads();
    {
        int r = t >> 4, c = (t & 15) * 2;
        float a0 = b1[c], a1 = b1[c + 1];
        const float* hr = &h0[r * 65];
        for (int k = 0; k < 64; ++k) {
            float xv = hr[k];
            a0 += xv * w1[k * 32 + c];
            a1 += xv * w1[k * 32 + c + 1];
        }
        h1[r * 33 + c]     = fmaxf(a0, 0.f);
        h1[r * 33 + c + 1] = fmaxf(a1, 0.f);
    }
    __syncthreads();
    if (t < 160) {
        int r = t / 10, c = t % 10;
        float a = b2[c];
        const float* hr = &h1[r * 33];
        for (int k = 0; k < 32; ++k) a += hr[k] * w2[k * 10 + c];
        outp[(size_t)(r0 + r) * 10 + c] = a;
    }
}

__global__ __launch_bounds__(256) void k_graph_mlp(
    const float* __restrict__ hg, const float* __restrict__ hgc,
    const float* __restrict__ Wg0, const float* __restrict__ bg0,
    const float* __restrict__ Wg1, const float* __restrict__ bg1,
    const float* __restrict__ Wg2, const float* __restrict__ bg2,
    float* __restrict__ outp)
{
    __shared__ float xs[32 * 257];
    __shared__ float h0[32 * 129];
    __shared__ float h1[32 * 65];
    int t = threadIdx.x;
    int row0 = blockIdx.x * 32;
    for (int i = t; i < 32 * 256; i += 256) {
        int r = row0 + (i >> 8);
        float v = (r < NG) ? hg[(size_t)r * 256 + (i & 255)]
                           : hgc[(size_t)(r - NG) * 256 + (i & 255)];
        xs[(i >> 8) * 257 + (i & 255)] = v;
    }
    __syncthreads();
    {
        int c = t & 127, rh = (t >> 7) * 16;
        float acc[16];
        float bb = bg0[c];
#pragma unroll
        for (int r = 0; r < 16; ++r) acc[r] = bb;
        for (int k = 0; k < 256; ++k) {
            float w = Wg0[(size_t)k * 128 + c];
#pragma unroll
            for (int r = 0; r < 16; ++r) acc[r] += xs[(rh + r) * 257 + k] * w;
        }
#pragma unroll
        for (int r = 0; r < 16; ++r) h0[(rh + r) * 129 + c] = fmaxf(acc[r], 0.f);
    }
    __syncthreads();
    {
        int c = t & 63, rq = (t >> 6) * 8;
        float acc[8];
        float bb = bg1[c];
#pragma unroll
        for (int r = 0; r < 8; ++r) acc[r] = bb;
        for (int k = 0; k < 128; ++k) {
            float w = Wg1[(size_t)k * 64 + c];
#pragma unroll
            for (int r = 0; r < 8; ++r) acc[r] += h0[(rq + r) * 129 + k] * w;
        }
#pragma unroll
        for (int r = 0; r < 8; ++r) h1[(rq + r) * 65 + c] = fmaxf(acc[r], 0.f);
    }
    __syncthreads();
    for (int idx = t; idx < 320; idx += 256) {
        int r = idx / 10, c = idx % 10;
        float a = bg2[c];
        for (int k = 0; k < 64; ++k) a += h1[r * 65 + k] * Wg2[k * 10 + c];
        outp[(size_t)(row0 + r) * 10 + c] = a;
    }
}

// ---------------------------------------------------------------------------
__global__ __launch_bounds__(256) void k_smax_part(const float* __restrict__ sc, float* __restrict__ pmax) {
    __shared__ float red[256];
    int t = threadIdx.x;
    float m = -INFINITY;
    for (int i = blockIdx.x * 256 + t; i < N1; i += 64 * 256) m = fmaxf(m, sc[i]);
    red[t] = m; __syncthreads();
    for (int off = 128; off > 0; off >>= 1) {
        if (t < off) red[t] = fmaxf(red[t], red[t + off]);
        __syncthreads();
    }
    if (t == 0) pmax[blockIdx.x] = red[0];
}
__global__ __launch_bounds__(256) void k_smax_sum(const float* __restrict__ sc, const float* __restrict__ pmax,
                                                 float* __restrict__ psum) {
    __shared__ float red[256];
    int t = threadIdx.x;
    float gm = -INFINITY;
#pragma unroll
    for (int i = 0; i < 64; ++i) gm = fmaxf(gm, pmax[i]);
    float s = 0.f;
    for (int i = blockIdx.x * 256 + t; i < N1; i += 64 * 256) s += expf(sc[i] - gm);
    red[t] = s; __syncthreads();
    for (int off = 128; off > 0; off >>= 1) {
        if (t < off) red[t] += red[t + off];
        __syncthreads();
    }
    if (t == 0) psum[blockIdx.x] = red[0];
}
__global__ __launch_bounds__(256) void k_smax_out(const float* __restrict__ sc, const float* __restrict__ pmax,
                                                 const float* __restrict__ psum, float* __restrict__ outp) {
    int t = threadIdx.x;
    float gm = -INFINITY; float gs = 0.f;
#pragma unroll
    for (int i = 0; i < 64; ++i) { gm = fmaxf(gm, pmax[i]); gs += psum[i]; }
    int i = blockIdx.x * 256 + t;
    outp[i] = expf(sc[i] - gm) / gs;
}

// ---------------------------------------------------------------------------
extern "C" void kernel_launch(void* const* d_in, const int* in_sizes, int n_in,
                              void* d_out, int out_size, void* d_ws, size_t ws_size,
                              hipStream_t stream) {
    const float* feature = (const float*)d_in[0];
    const int*   src     = (const int*)d_in[1];
    const int*   dst     = (const int*)d_in[2];
    const float* W1  = (const float*)d_in[4];
    const float* b1  = (const float*)d_in[5];
    const float* W2  = (const float*)d_in[6];
    const float* b2  = (const float*)d_in[7];
    const float* W3  = (const float*)d_in[8];
    const float* b3  = (const float*)d_in[9];
    const float* Wsv = (const float*)d_in[10];
    const float* bsv = (const float*)d_in[11];
    const float* Wg0 = (const float*)d_in[12];
    const float* bg0 = (const float*)d_in[13];
    const float* Wg1 = (const float*)d_in[14];
    const float* bg1 = (const float*)d_in[15];
    const float* Wg2 = (const float*)d_in[16];
    const float* bg2 = (const float*)d_in[17];
    const float* Wp0 = (const float*)d_in[18];
    const float* bp0 = (const float*)d_in[19];
    const float* Wp1 = (const float*)d_in[20];
    const float* bp1 = (const float*)d_in[21];
    const float* Wp2 = (const float*)d_in[22];
    const float* bp2 = (const float*)d_in[23];

    float* out = (float*)d_out;
    float* o_scores    = out;            // [512][10]
    float* o_hg3com    = out + 5120;     // [256][256]
    float* o_nodepred  = out + 70656;    // [16384][10]
    float* o_nodescore = out + 234496;   // [65536]

    float* ws = (float*)d_ws;
    size_t off = 0;
    auto alloc_f = [&](size_t n) { float* p = ws + off; off += (n + 63) & ~(size_t)63; return p; };
    float* agg    = alloc_f(8388608);   // [65536][128]
    float* outbuf = alloc_f(8388608);
    float* f1d    = alloc_f(4194304);
    float* f2d    = alloc_f(2097152);
    u16*   bucket = (u16*)alloc_f(2097152);   // [65536][64] ushort
    int*   src2   = (int*)alloc_f(1048576);
    int*   dst2   = (int*)alloc_f(1048576);
    int*   src3   = (int*)alloc_f(1048576);
    int*   dst3   = (int*)alloc_f(1048576);
    int*   cnt_in = (int*)alloc_f(65536);
    int*   cnt_out= (int*)alloc_f(65536);
    float* tbuf   = alloc_f(65536);
    float* gate   = alloc_f(65536);
    float* score1 = alloc_f(65536);
    float* scoreX = alloc_f(65536);
    int*   perm_d = (int*)alloc_f(32768);
    int*   perm_c = (int*)alloc_f(32768);
    float* hg     = alloc_f(65536);
    float* hg_com = alloc_f(65536);
    float* pmax   = alloc_f(64);
    float* psum   = alloc_f(64);
    (void)ws_size; (void)in_sizes; (void)n_in; (void)out_size;

    hipMemsetAsync(hg, 0, 2 * 65536 * sizeof(float), stream);

    // =================== stage 1 (N=65536, np=256, k=128) ==================
    hipMemsetAsync(cnt_in, 0, 2 * 65536 * sizeof(int), stream);
    k_build<<<NEDGE / 256, 256, 0, stream>>>(src, dst, cnt_in, cnt_out, bucket, 255);
    k_agg_g<256><<<NG, 512, 0, stream>>>(feature, bucket, cnt_in, cnt_out, agg);
    k_gemm<<<65536 / 128, 256, 0, stream>>>(agg, W1, b1, feature, Wsv, cnt_out, outbuf, tbuf);
    k_pool<256, 128, true><<<NG, 256, 0, stream>>>(tbuf, bucket, cnt_in, bsv, src, dst,
                                                   score1, gate, perm_d, perm_c, src2, dst2);
    k_gather<<<NG * 128, 128, 0, stream>>>(outbuf, gate, perm_d, f1d);
    k_readout<<<2 * NG, 128, 0, stream>>>(outbuf, gate, perm_d, perm_c, 128, hg, hg_com, nullptr);

    // =================== stage 2 (N=32768, np=128, k=64) ===================
    hipMemsetAsync(cnt_in, 0, 2 * 65536 * sizeof(int), stream);
    k_build<<<NEDGE / 256, 256, 0, stream>>>(src2, dst2, cnt_in, cnt_out, bucket, 127);
    k_agg_g<128><<<NG, 512, 0, stream>>>(f1d, bucket, cnt_in, cnt_out, agg);
    k_gemm<<<32768 / 128, 256, 0, stream>>>(agg, W2, b2, f1d, Wsv, cnt_out, outbuf, tbuf);
    k_pool<128, 64, true><<<NG, 128, 0, stream>>>(tbuf, bucket, cnt_in, bsv, src2, dst2,
                                                  scoreX, gate, perm_d, perm_c, src3, dst3);
    k_gather<<<NG * 64, 128, 0, stream>>>(outbuf, gate, perm_d, f2d);
    k_readout<<<2 * NG, 128, 0, stream>>>(outbuf, gate, perm_d, perm_c, 64, hg, hg_com, nullptr);

    // =================== stage 3 (N=16384, np=64, k=32) ====================
    hipMemsetAsync(cnt_in, 0, 2 * 65536 * sizeof(int), stream);
    k_build<<<NEDGE / 256, 256, 0, stream>>>(src3, dst3, cnt_in, cnt_out, bucket, 63);
    k_agg_g<64><<<NG, 512, 0, stream>>>(f2d, bucket, cnt_in, cnt_out, agg);
    k_gemm<<<16384 / 128, 256, 0, stream>>>(agg, W3, b3, f2d, Wsv, cnt_out, outbuf, tbuf);
    k_pool<64, 32, false><<<NG, 64, 0, stream>>>(tbuf, bucket, cnt_in, bsv, nullptr, nullptr,
                                                 scoreX, gate, perm_d, perm_c, nullptr, nullptr);
    k_readout<<<2 * NG, 128, 0, stream>>>(outbuf, gate, perm_d, perm_c, 32, hg, hg_com, o_hg3com);

    // =================== heads =============================================
    k_node_mlp<<<16384 / 16, 256, 0, stream>>>(outbuf, Wp0, bp0, Wp1, bp1, Wp2, bp2, o_nodepred);
    k_graph_mlp<<<16, 256, 0, stream>>>(hg, hg_com, Wg0, bg0, Wg1, bg1, Wg2, bg2, o_scores);
    k_smax_part<<<64, 256, 0, stream>>>(score1, pmax);
    k_smax_sum<<<64, 256, 0, stream>>>(score1, pmax, psum);
    k_smax_out<<<N1 / 256, 256, 0, stream>>>(score1, pmax, psum, o_nodescore);
}

// Round 6
// 428.172 us; speedup vs baseline: 1.3690x; 1.3638x over previous
//
#include <hip/hip_runtime.h>
#include <math.h>

#define NG    256          // graphs
#define D     128          // feature dim
#define EPG   4096         // edge capacity per graph (constant across stages)
#define NEDGE (NG*EPG)     // 1048576
#define CAP   48           // incoming-edge bucket capacity per node (P(deg>48) ~ 6e-11)
#define N1    65536        // stage-1 node count

typedef unsigned short u16;
typedef unsigned int   u32;

// ---------------------------------------------------------------------------
// Fused per-graph build + aggregate. One 512-thread block per graph:
//  pass A: read this graph's 4096 edges coalesced; degree counts + incoming-
//          edge bucket entirely in LDS (ds atomics — no global atomics at all)
//  pass B: scl = rsqrt(max(deg_out,1)); dump cnt_in/scl/bucket to global
//          (coalesced) for k_pool / k_gemm
//  pass C: stage features scaled by scl into LDS
//  pass D: per-wave node aggregation: bucket row from LDS, readlane broadcast,
//          conflict-free float2 LDS gathers (full 512B row per instruction)
template<int NPn>
__global__ __launch_bounds__(512) void k_agg_build(
    const float* __restrict__ x, const int* __restrict__ srcE, const int* __restrict__ dstE,
    float* __restrict__ agg, u16* __restrict__ bucket_g,
    int* __restrict__ cnt_in_g, float* __restrict__ sclg)
{
    __shared__ float feat[NPn * 128];     // 128 KB at NPn=256
    __shared__ u16   bkt[NPn * CAP];      // 24 KB at NPn=256
    __shared__ int   cin[NPn];
    __shared__ int   cout[NPn];           // reused as float scl after barrier
    const int g = ((blockIdx.x & 7) << 5) | (blockIdx.x >> 3);  // graph g on XCD g/32
    const int t = threadIdx.x;

    for (int i = t; i < NPn; i += 512) { cin[i] = 0; cout[i] = 0; }
    __syncthreads();

    // ---- pass A: count + bucket-fill via LDS atomics ----------------------
    for (int e = g * EPG + t; e < (g + 1) * EPG; e += 512) {
        int s = srcE[e];
        if (s >= 0) {
            int d  = dstE[e];
            int sl = s - g * NPn;
            int dl = d - g * NPn;
            atomicAdd(&cout[sl], 1);
            int pos = atomicAdd(&cin[dl], 1);
            if (pos < CAP) bkt[dl * CAP + pos] = (u16)sl;
        }
    }
    __syncthreads();

    // ---- pass B: scl + global dumps ---------------------------------------
    float* scll = (float*)cout;
    for (int i = t; i < NPn; i += 512) {
        cnt_in_g[g * NPn + i] = cin[i];
        float sc = rsqrtf((float)max(cout[i], 1));
        sclg[g * NPn + i] = sc;
        scll[i] = sc;                      // overwrite int count with float scl
    }
    __syncthreads();

    // ---- pass C: stage features scaled by scl -----------------------------
    for (int idx = t; idx < NPn * 32; idx += 512) {
        int r = idx >> 5, q = idx & 31;
        float4 v = *(const float4*)&x[((size_t)(g * NPn + r)) * D + q * 4];
        float s = scll[r];
        v.x *= s; v.y *= s; v.z *= s; v.w *= s;
        *(float4*)&feat[r * 128 + q * 4] = v;
    }
    // dump bucket to global (coalesced u32 view) for k_pool
    {
        const int nw = NPn * CAP / 2;
        const u32* bw = (const u32*)bkt;
        u32* bg = (u32*)(bucket_g + (size_t)g * NPn * CAP);
        for (int i = t; i < nw; i += 512) bg[i] = bw[i];
    }
    __syncthreads();

    // ---- pass D: aggregate ------------------------------------------------
    const int w = t >> 6, l = t & 63;
    for (int n = w; n < NPn; n += 8) {
        int cnt = __builtin_amdgcn_readfirstlane(min(cin[n], CAP));
        int bv = (l < cnt) ? (int)bkt[n * CAP + l] : 0;
        float ax = 0.f, ay = 0.f;
        int i = 0;
        for (; i + 2 <= cnt; i += 2) {
            int s0 = __builtin_amdgcn_readlane(bv, i);
            int s1 = __builtin_amdgcn_readlane(bv, i + 1);
            float2 v0 = *(const float2*)&feat[s0 * 128 + 2 * l];
            float2 v1 = *(const float2*)&feat[s1 * 128 + 2 * l];
            ax += v0.x; ay += v0.y; ax += v1.x; ay += v1.y;
        }
        if (i < cnt) {
            int s0 = __builtin_amdgcn_readlane(bv, i);
            float2 v0 = *(const float2*)&feat[s0 * 128 + 2 * l];
            ax += v0.x; ay += v0.y;
        }
        float sc = rsqrtf((float)max(cnt, 1));
        *(float2*)&agg[((size_t)(g * NPn + n)) * D + 2 * l] = make_float2(ax * sc, ay * sc);
    }
}

// ---------------------------------------------------------------------------
// out = res + relu(agg @ W + b); epilogue also emits t[n] = dot(out[n],Ws)*scl[n].
__global__ __launch_bounds__(256) void k_gemm(
    const float* __restrict__ A, const float* __restrict__ Wm,
    const float* __restrict__ bias, const float* __restrict__ res,
    const float* __restrict__ Wsv, const float* __restrict__ sclg,
    float* __restrict__ outp, float* __restrict__ tbuf)
{
    __shared__ float4 At4[32 * 33];   // [perm(r/4)][kl]  rows of A (transposed)
    __shared__ float4 Wt4[32 * 33];   // [perm(c/4)][kl]
    __shared__ float  Wsl[128];
    __shared__ float  part[128 * 17];
    const int t  = threadIdx.x;
    const int tr = t >> 4;            // 0..15 : rows 8tr..8tr+7
    const int tc = t & 15;            // 0..15 : cols 8tc..8tc+7
    const int cb = tc * 8;
    const int lb = ((blockIdx.x & 7) * (gridDim.x >> 3)) + (blockIdx.x >> 3);
    const size_t r0 = (size_t)lb * 128;

    if (t < 128) Wsl[t] = Wsv[t];

    float acc[8][8];
#pragma unroll
    for (int i = 0; i < 8; ++i)
#pragma unroll
        for (int j = 0; j < 8; ++j) acc[i][j] = 0.f;

    for (int ph = 0; ph < 4; ++ph) {
        __syncthreads();
#pragma unroll
        for (int s2 = 0; s2 < 4; ++s2) {
            int idx = t + 256 * s2;
            int r  = idx >> 3;        // 0..127
            int kc = idx & 7;         // 0..7
            float4 v = *(const float4*)&A[(r0 + r) * D + ph * 32 + kc * 4];
            int r4 = r >> 2, lane = r & 3;
            int prow = (r4 >> 1) | ((r4 & 1) << 4);
            float* base = (float*)&At4[prow * 33 + kc * 4];
            base[0  + lane] = v.x;
            base[4  + lane] = v.y;
            base[8  + lane] = v.z;
            base[12 + lane] = v.w;
        }
#pragma unroll
        for (int s2 = 0; s2 < 4; ++s2) {
            int idx = t + 256 * s2;
            int wr  = idx >> 5;       // 0..31 (k)
            int wc4 = idx & 31;       // col quad
            float4 v = *(const float4*)&Wm[(size_t)(ph * 32 + wr) * D + wc4 * 4];
            int pcol = (wc4 >> 1) | ((wc4 & 1) << 4);
            Wt4[pcol * 33 + wr] = v;
        }
        __syncthreads();
#pragma unroll 4
        for (int kl = 0; kl < 32; ++kl) {
            float4 a0 = At4[tr * 33 + kl];
            float4 a1 = At4[(tr + 16) * 33 + kl];
            float4 w0 = Wt4[tc * 33 + kl];
            float4 w1 = Wt4[(tc + 16) * 33 + kl];
            float av[8] = {a0.x, a0.y, a0.z, a0.w, a1.x, a1.y, a1.z, a1.w};
            float wv[8] = {w0.x, w0.y, w0.z, w0.w, w1.x, w1.y, w1.z, w1.w};
#pragma unroll
            for (int i = 0; i < 8; ++i)
#pragma unroll
                for (int j = 0; j < 8; ++j)
                    acc[i][j] += av[i] * wv[j];
        }
    }
    __syncthreads();
    float bv[8];
#pragma unroll
    for (int j = 0; j < 8; ++j) bv[j] = bias[cb + j];
#pragma unroll
    for (int i = 0; i < 8; ++i) {
        size_t row = r0 + tr * 8 + i;
        float4 rA = *(const float4*)&res[row * D + cb];
        float4 rB = *(const float4*)&res[row * D + cb + 4];
        float o0 = rA.x + fmaxf(acc[i][0] + bv[0], 0.f);
        float o1 = rA.y + fmaxf(acc[i][1] + bv[1], 0.f);
        float o2 = rA.z + fmaxf(acc[i][2] + bv[2], 0.f);
        float o3 = rA.w + fmaxf(acc[i][3] + bv[3], 0.f);
        float o4 = rB.x + fmaxf(acc[i][4] + bv[4], 0.f);
        float o5 = rB.y + fmaxf(acc[i][5] + bv[5], 0.f);
        float o6 = rB.z + fmaxf(acc[i][6] + bv[6], 0.f);
        float o7 = rB.w + fmaxf(acc[i][7] + bv[7], 0.f);
        *(float4*)&outp[row * D + cb]     = make_float4(o0, o1, o2, o3);
        *(float4*)&outp[row * D + cb + 4] = make_float4(o4, o5, o6, o7);
        float p = o0 * Wsl[cb + 0] + o1 * Wsl[cb + 1] + o2 * Wsl[cb + 2] + o3 * Wsl[cb + 3]
                + o4 * Wsl[cb + 4] + o5 * Wsl[cb + 5] + o6 * Wsl[cb + 6] + o7 * Wsl[cb + 7];
        part[(tr * 8 + i) * 17 + tc] = p;
    }
    __syncthreads();
    if (t < 128) {
        float s = 0.f;
#pragma unroll
        for (int j = 0; j < 16; ++j) s += part[t * 17 + j];
        size_t n = r0 + t;
        tbuf[n] = s * sclg[n];
    }
}

// ---------------------------------------------------------------------------
// Per-graph pooling: score via pushed-through scalar GraphConv, exact top-k by
// rank counting, dis/com permutations, edge remap. Bucket entries are LOCAL ids.
template<int NPn, int K, bool REMAP>
__global__ __launch_bounds__(NPn) void k_pool(
    const float* __restrict__ tbuf, const u16* __restrict__ bucket,
    const int* __restrict__ cnt_in, const float* __restrict__ bsv,
    const int* __restrict__ srcE, const int* __restrict__ dstE,
    float* __restrict__ score_out, float* __restrict__ gate_out,
    int* __restrict__ perm_dis, int* __restrict__ perm_com,
    int* __restrict__ src_next, int* __restrict__ dst_next)
{
    __shared__ float sc[NPn];
    __shared__ int   pf[NPn];
    __shared__ int   lid[NPn];
    const int g = ((blockIdx.x & 7) << 5) | (blockIdx.x >> 3);
    const int t = threadIdx.x;
    const int n = g * NPn + t;

    int cnt = cnt_in[n]; if (cnt > CAP) cnt = CAP;
    const u16* bk = bucket + (size_t)n * CAP;
    float a = 0.f;
    int i = 0;
    for (; i + 2 <= cnt; i += 2) {
        float v0 = tbuf[g * NPn + bk[i]];
        float v1 = tbuf[g * NPn + bk[i + 1]];
        a += v0; a += v1;
    }
    if (i < cnt) a += tbuf[g * NPn + bk[i]];
    float my = a * rsqrtf((float)max(cnt, 1)) + bsv[0];
    score_out[n] = my;
    gate_out[n]  = tanhf(my);
    sc[t] = my;
    __syncthreads();

    int rank = 0;
    for (int j = 0; j < NPn; ++j) {
        float v = sc[j];
        rank += (int)((v > my) || (v == my && j < t));
    }
    const int kept = (rank < K) ? 1 : 0;
    pf[t] = kept;
    __syncthreads();
    int val = kept;
    for (int off = 1; off < NPn; off <<= 1) {
        int add = (t >= off) ? pf[t - off] : 0;
        __syncthreads();
        val += add;
        pf[t] = val;
        __syncthreads();
    }
    int excl = val - kept;
    if (kept) { lid[t] = excl;  perm_dis[g * K + excl] = n; }
    else      { lid[t] = -1;    perm_com[g * (NPn - K) + (t - excl)] = n; }
    __syncthreads();

    if (REMAP) {
        for (int e = g * EPG + t; e < (g + 1) * EPG; e += NPn) {
            int s = srcE[e];
            int ns = -1, nd = -1;
            if (s >= 0) {
                int ls  = lid[s - g * NPn];
                int ld2 = lid[dstE[e] - g * NPn];
                if (ls >= 0 && ld2 >= 0) { ns = g * K + ls; nd = g * K + ld2; }
            }
            src_next[e] = ns;
            dst_next[e] = nd;
        }
    }
}

// ---------------------------------------------------------------------------
__global__ __launch_bounds__(128) void k_gather(
    const float* __restrict__ x, const float* __restrict__ gate,
    const int* __restrict__ perm, float* __restrict__ outf)
{
    int i = blockIdx.x, t = threadIdx.x;
    int old = perm[i];
    outf[(size_t)i * D + t] = x[(size_t)old * D + t] * gate[old];
}

__global__ __launch_bounds__(128) void k_readout(
    const float* __restrict__ x, const float* __restrict__ gate,
    const int* __restrict__ perm_dis, const int* __restrict__ perm_com,
    int kcnt, float* __restrict__ hg, float* __restrict__ hgc,
    float* __restrict__ copy_com)
{
    int b = blockIdx.x, t = threadIdx.x;
    int com = (b >= NG) ? 1 : 0;
    int g = com ? b - NG : b;
    const int* perm = (com ? perm_com : perm_dis) + (size_t)g * kcnt;
    float sm = 0.f, mx = -INFINITY;
    int r = 0;
    for (; r + 4 <= kcnt; r += 4) {   // 4 rows in flight
        int o0 = perm[r], o1 = perm[r + 1], o2 = perm[r + 2], o3 = perm[r + 3];
        float v0 = x[(size_t)o0 * D + t] * gate[o0];
        float v1 = x[(size_t)o1 * D + t] * gate[o1];
        float v2 = x[(size_t)o2 * D + t] * gate[o2];
        float v3 = x[(size_t)o3 * D + t] * gate[o3];
        sm += v0; mx = fmaxf(mx, v0);
        sm += v1; mx = fmaxf(mx, v1);
        sm += v2; mx = fmaxf(mx, v2);
        sm += v3; mx = fmaxf(mx, v3);
    }
    for (; r < kcnt; ++r) {
        int o0 = perm[r];
        float v = x[(size_t)o0 * D + t] * gate[o0];
        sm += v; mx = fmaxf(mx, v);
    }
    float mean = sm * (1.f / (float)kcnt);
    float* dstp = com ? hgc : hg;
    dstp[(size_t)g * 256 + t]       += mean;
    dstp[(size_t)g * 256 + 128 + t] += mx;
    if (com && copy_com) {
        copy_com[(size_t)g * 256 + t]       = mean;
        copy_com[(size_t)g * 256 + 128 + t] = mx;
    }
}

// ---------------------------------------------------------------------------
__global__ __launch_bounds__(256) void k_node_mlp(
    const float* __restrict__ X,
    const float* __restrict__ W0, const float* __restrict__ b0,
    const float* __restrict__ W1, const float* __restrict__ b1,
    const float* __restrict__ W2, const float* __restrict__ b2,
    float* __restrict__ outp)
{
    __shared__ float xs[16 * 132];
    __shared__ float w0[128 * 64];
    __shared__ float h0[16 * 65];
    __shared__ float w1[64 * 32];
    __shared__ float h1[16 * 33];
    __shared__ float w2[32 * 10];
    int t = threadIdx.x;
    int r0 = blockIdx.x * 16;
    for (int i = t; i < 128 * 64; i += 256) w0[i] = W0[i];
    for (int i = t; i < 64 * 32;  i += 256) w1[i] = W1[i];
    for (int i = t; i < 320;      i += 256) w2[i] = W2[i];
    for (int i = t; i < 16 * 128; i += 256)
        xs[(i >> 7) * 132 + (i & 127)] = X[(size_t)(r0 + (i >> 7)) * D + (i & 127)];
    __syncthreads();
    {
        int r = t >> 4, c = (t & 15) * 4;
        float a0 = b0[c], a1 = b0[c + 1], a2 = b0[c + 2], a3 = b0[c + 3];
        const float* xr = &xs[r * 132];
        for (int k = 0; k < 128; ++k) {
            float xv = xr[k];
            float4 w = *(const float4*)&w0[k * 64 + c];
            a0 += xv * w.x; a1 += xv * w.y; a2 += xv * w.z; a3 += xv * w.w;
        }
        float* hr = &h0[r * 65 + c];
        hr[0] = fmaxf(a0, 0.f); hr[1] = fmaxf(a1, 0.f); hr[2] = fmaxf(a2, 0.f); hr[3] = fmaxf(a3, 0.f);
    }
    __syncthreads();
    {
        int r = t >> 4, c = (t & 15) * 2;
        float a0 = b1[c], a1 = b1[c + 1];
        const float* hr = &h0[r * 65];
        for (int k = 0; k < 64; ++k) {
            float xv = hr[k];
            a0 += xv * w1[k * 32 + c];
            a1 += xv * w1[k * 32 + c + 1];
        }
        h1[r * 33 + c]     = fmaxf(a0, 0.f);
        h1[r * 33 + c + 1] = fmaxf(a1, 0.f);
    }
    __syncthreads();
    if (t < 160) {
        int r = t / 10, c = t % 10;
        float a = b2[c];
        const float* hr = &h1[r * 33];
        for (int k = 0; k < 32; ++k) a += hr[k] * w2[k * 10 + c];
        outp[(size_t)(r0 + r) * 10 + c] = a;
    }
}

__global__ __launch_bounds__(256) void k_graph_mlp(
    const float* __restrict__ hg, const float* __restrict__ hgc,
    const float* __restrict__ Wg0, const float* __restrict__ bg0,
    const float* __restrict__ Wg1, const float* __restrict__ bg1,
    const float* __restrict__ Wg2, const float* __restrict__ bg2,
    float* __restrict__ outp)
{
    __shared__ float xs[32 * 257];
    __shared__ float h0[32 * 129];
    __shared__ float h1[32 * 65];
    int t = threadIdx.x;
    int row0 = blockIdx.x * 32;
    for (int i = t; i < 32 * 256; i += 256) {
        int r = row0 + (i >> 8);
        float v = (r < NG) ? hg[(size_t)r * 256 + (i & 255)]
                           : hgc[(size_t)(r - NG) * 256 + (i & 255)];
        xs[(i >> 8) * 257 + (i & 255)] = v;
    }
    __syncthreads();
    {
        int c = t & 127, rh = (t >> 7) * 16;
        float acc[16];
        float bb = bg0[c];
#pragma unroll
        for (int r = 0; r < 16; ++r) acc[r] = bb;
        for (int k = 0; k < 256; ++k) {
            float w = Wg0[(size_t)k * 128 + c];
#pragma unroll
            for (int r = 0; r < 16; ++r) acc[r] += xs[(rh + r) * 257 + k] * w;
        }
#pragma unroll
        for (int r = 0; r < 16; ++r) h0[(rh + r) * 129 + c] = fmaxf(acc[r], 0.f);
    }
    __syncthreads();
    {
        int c = t & 63, rq = (t >> 6) * 8;
        float acc[8];
        float bb = bg1[c];
#pragma unroll
        for (int r = 0; r < 8; ++r) acc[r] = bb;
        for (int k = 0; k < 128; ++k) {
            float w = Wg1[(size_t)k * 64 + c];
#pragma unroll
            for (int r = 0; r < 8; ++r) acc[r] += h0[(rq + r) * 129 + k] * w;
        }
#pragma unroll
        for (int r = 0; r < 8; ++r) h1[(rq + r) * 65 + c] = fmaxf(acc[r], 0.f);
    }
    __syncthreads();
    for (int idx = t; idx < 320; idx += 256) {
        int r = idx / 10, c = idx % 10;
        float a = bg2[c];
        for (int k = 0; k < 64; ++k) a += h1[r * 65 + k] * Wg2[k * 10 + c];
        outp[(size_t)(row0 + r) * 10 + c] = a;
    }
}

// ---------------------------------------------------------------------------
__global__ __launch_bounds__(256) void k_smax_part(const float* __restrict__ sc, float* __restrict__ pmax) {
    __shared__ float red[256];
    int t = threadIdx.x;
    float m = -INFINITY;
    for (int i = blockIdx.x * 256 + t; i < N1; i += 64 * 256) m = fmaxf(m, sc[i]);
    red[t] = m; __syncthreads();
    for (int off = 128; off > 0; off >>= 1) {
        if (t < off) red[t] = fmaxf(red[t], red[t + off]);
        __syncthreads();
    }
    if (t == 0) pmax[blockIdx.x] = red[0];
}
__global__ __launch_bounds__(256) void k_smax_sum(const float* __restrict__ sc, const float* __restrict__ pmax,
                                                 float* __restrict__ psum) {
    __shared__ float red[256];
    int t = threadIdx.x;
    float gm = -INFINITY;
#pragma unroll
    for (int i = 0; i < 64; ++i) gm = fmaxf(gm, pmax[i]);
    float s = 0.f;
    for (int i = blockIdx.x * 256 + t; i < N1; i += 64 * 256) s += expf(sc[i] - gm);
    red[t] = s; __syncthreads();
    for (int off = 128; off > 0; off >>= 1) {
        if (t < off) red[t] += red[t + off];
        __syncthreads();
    }
    if (t == 0) psum[blockIdx.x] = red[0];
}
__global__ __launch_bounds__(256) void k_smax_out(const float* __restrict__ sc, const float* __restrict__ pmax,
                                                 const float* __restrict__ psum, float* __restrict__ outp) {
    int t = threadIdx.x;
    float gm = -INFINITY; float gs = 0.f;
#pragma unroll
    for (int i = 0; i < 64; ++i) { gm = fmaxf(gm, pmax[i]); gs += psum[i]; }
    int i = blockIdx.x * 256 + t;
    outp[i] = expf(sc[i] - gm) / gs;
}

// ---------------------------------------------------------------------------
extern "C" void kernel_launch(void* const* d_in, const int* in_sizes, int n_in,
                              void* d_out, int out_size, void* d_ws, size_t ws_size,
                              hipStream_t stream) {
    const float* feature = (const float*)d_in[0];
    const int*   src     = (const int*)d_in[1];
    const int*   dst     = (const int*)d_in[2];
    const float* W1  = (const float*)d_in[4];
    const float* b1  = (const float*)d_in[5];
    const float* W2  = (const float*)d_in[6];
    const float* b2  = (const float*)d_in[7];
    const float* W3  = (const float*)d_in[8];
    const float* b3  = (const float*)d_in[9];
    const float* Wsv = (const float*)d_in[10];
    const float* bsv = (const float*)d_in[11];
    const float* Wg0 = (const float*)d_in[12];
    const float* bg0 = (const float*)d_in[13];
    const float* Wg1 = (const float*)d_in[14];
    const float* bg1 = (const float*)d_in[15];
    const float* Wg2 = (const float*)d_in[16];
    const float* bg2 = (const float*)d_in[17];
    const float* Wp0 = (const float*)d_in[18];
    const float* bp0 = (const float*)d_in[19];
    const float* Wp1 = (const float*)d_in[20];
    const float* bp1 = (const float*)d_in[21];
    const float* Wp2 = (const float*)d_in[22];
    const float* bp2 = (const float*)d_in[23];

    float* out = (float*)d_out;
    float* o_scores    = out;            // [512][10]
    float* o_hg3com    = out + 5120;     // [256][256]
    float* o_nodepred  = out + 70656;    // [16384][10]
    float* o_nodescore = out + 234496;   // [65536]

    float* ws = (float*)d_ws;
    size_t off = 0;
    auto alloc_f = [&](size_t n) { float* p = ws + off; off += (n + 63) & ~(size_t)63; return p; };
    float* agg    = alloc_f(8388608);   // [65536][128]
    float* outbuf = alloc_f(8388608);
    float* f1d    = alloc_f(4194304);
    float* f2d    = alloc_f(2097152);
    u16*   bucket = (u16*)alloc_f(1572864);   // [65536][48] ushort
    int*   src2   = (int*)alloc_f(1048576);
    int*   dst2   = (int*)alloc_f(1048576);
    int*   src3   = (int*)alloc_f(1048576);
    int*   dst3   = (int*)alloc_f(1048576);
    int*   cnt_in = (int*)alloc_f(65536);
    float* sclg   = alloc_f(65536);
    float* tbuf   = alloc_f(65536);
    float* gate   = alloc_f(65536);
    float* score1 = alloc_f(65536);
    float* scoreX = alloc_f(65536);
    int*   perm_d = (int*)alloc_f(32768);
    int*   perm_c = (int*)alloc_f(32768);
    float* hg     = alloc_f(65536);
    float* hg_com = alloc_f(65536);
    float* pmax   = alloc_f(64);
    float* psum   = alloc_f(64);
    (void)ws_size; (void)in_sizes; (void)n_in; (void)out_size;

    hipMemsetAsync(hg, 0, 2 * 65536 * sizeof(float), stream);

    // =================== stage 1 (N=65536, np=256, k=128) ==================
    k_agg_build<256><<<NG, 512, 0, stream>>>(feature, src, dst, agg, bucket, cnt_in, sclg);
    k_gemm<<<65536 / 128, 256, 0, stream>>>(agg, W1, b1, feature, Wsv, sclg, outbuf, tbuf);
    k_pool<256, 128, true><<<NG, 256, 0, stream>>>(tbuf, bucket, cnt_in, bsv, src, dst,
                                                   score1, gate, perm_d, perm_c, src2, dst2);
    k_gather<<<NG * 128, 128, 0, stream>>>(outbuf, gate, perm_d, f1d);
    k_readout<<<2 * NG, 128, 0, stream>>>(outbuf, gate, perm_d, perm_c, 128, hg, hg_com, nullptr);

    // =================== stage 2 (N=32768, np=128, k=64) ===================
    k_agg_build<128><<<NG, 512, 0, stream>>>(f1d, src2, dst2, agg, bucket, cnt_in, sclg);
    k_gemm<<<32768 / 128, 256, 0, stream>>>(agg, W2, b2, f1d, Wsv, sclg, outbuf, tbuf);
    k_pool<128, 64, true><<<NG, 128, 0, stream>>>(tbuf, bucket, cnt_in, bsv, src2, dst2,
                                                  scoreX, gate, perm_d, perm_c, src3, dst3);
    k_gather<<<NG * 64, 128, 0, stream>>>(outbuf, gate, perm_d, f2d);
    k_readout<<<2 * NG, 128, 0, stream>>>(outbuf, gate, perm_d, perm_c, 64, hg, hg_com, nullptr);

    // =================== stage 3 (N=16384, np=64, k=32) ====================
    k_agg_build<64><<<NG, 512, 0, stream>>>(f2d, src3, dst3, agg, bucket, cnt_in, sclg);
    k_gemm<<<16384 / 128, 256, 0, stream>>>(agg, W3, b3, f2d, Wsv, sclg, outbuf, tbuf);
    k_pool<64, 32, false><<<NG, 64, 0, stream>>>(tbuf, bucket, cnt_in, bsv, nullptr, nullptr,
                                                 scoreX, gate, perm_d, perm_c, nullptr, nullptr);
    k_readout<<<2 * NG, 128, 0, stream>>>(outbuf, gate, perm_d, perm_c, 32, hg, hg_com, o_hg3com);

    // =================== heads =============================================
    k_node_mlp<<<16384 / 16, 256, 0, stream>>>(outbuf, Wp0, bp0, Wp1, bp1, Wp2, bp2, o_nodepred);
    k_graph_mlp<<<16, 256, 0, stream>>>(hg, hg_com, Wg0, bg0, Wg1, bg1, Wg2, bg2, o_scores);
    k_smax_part<<<64, 256, 0, stream>>>(score1, pmax);
    k_smax_sum<<<64, 256, 0, stream>>>(score1, pmax, psum);
    k_smax_out<<<N1 / 256, 256, 0, stream>>>(score1, pmax, psum, o_nodescore);
}

// Round 8
// 399.844 us; speedup vs baseline: 1.4660x; 1.0708x over previous
//
#include <hip/hip_runtime.h>
#include <math.h>

#define NG    256          // graphs
#define D     128          // feature dim
#define EPG   4096         // edge capacity per graph (constant across stages)
#define NEDGE (NG*EPG)     // 1048576
#define CAP   48           // incoming-edge bucket capacity per node (P(deg>48) ~ 6e-11)
#define N1    65536        // stage-1 node count

typedef unsigned short u16;
typedef unsigned int   u32;

// ---------------------------------------------------------------------------
// Fused per-graph build + aggregate. One 512-thread block per graph:
//  pass A: read this graph's 4096 edges coalesced; degree counts + incoming-
//          edge bucket entirely in LDS (ds atomics — no global atomics at all)
//  pass B: scl = rsqrt(max(deg_out,1)); dump cnt_in/scl/bucket to global
//  pass C: stage features scaled by scl into LDS
//  pass D: per-wave node aggregation via readlane broadcast + float2 LDS reads
template<int NPn>
__global__ __launch_bounds__(512) void k_agg_build(
    const float* __restrict__ x, const int* __restrict__ srcE, const int* __restrict__ dstE,
    float* __restrict__ agg, u16* __restrict__ bucket_g,
    int* __restrict__ cnt_in_g, float* __restrict__ sclg)
{
    __shared__ float feat[NPn * 128];     // 128 KB at NPn=256
    __shared__ u16   bkt[NPn * CAP];      // 24 KB at NPn=256
    __shared__ int   cin[NPn];
    __shared__ int   cout[NPn];           // reused as float scl after barrier
    const int g = ((blockIdx.x & 7) << 5) | (blockIdx.x >> 3);  // graph g on XCD g/32
    const int t = threadIdx.x;

    for (int i = t; i < NPn; i += 512) { cin[i] = 0; cout[i] = 0; }
    __syncthreads();

    // ---- pass A: count + bucket-fill via LDS atomics ----------------------
    for (int e = g * EPG + t; e < (g + 1) * EPG; e += 512) {
        int s = srcE[e];
        if (s >= 0) {
            int d  = dstE[e];
            int sl = s - g * NPn;
            int dl = d - g * NPn;
            atomicAdd(&cout[sl], 1);
            int pos = atomicAdd(&cin[dl], 1);
            if (pos < CAP) bkt[dl * CAP + pos] = (u16)sl;
        }
    }
    __syncthreads();

    // ---- pass B: scl + global dumps ---------------------------------------
    float* scll = (float*)cout;
    for (int i = t; i < NPn; i += 512) {
        cnt_in_g[g * NPn + i] = cin[i];
        float sc = rsqrtf((float)max(cout[i], 1));
        sclg[g * NPn + i] = sc;
        scll[i] = sc;                      // overwrite int count with float scl
    }
    __syncthreads();

    // ---- pass C: stage features scaled by scl -----------------------------
    for (int idx = t; idx < NPn * 32; idx += 512) {
        int r = idx >> 5, q = idx & 31;
        float4 v = *(const float4*)&x[((size_t)(g * NPn + r)) * D + q * 4];
        float s = scll[r];
        v.x *= s; v.y *= s; v.z *= s; v.w *= s;
        *(float4*)&feat[r * 128 + q * 4] = v;
    }
    // dump bucket to global (coalesced u32 view) for k_pool
    {
        const int nw = NPn * CAP / 2;
        const u32* bw = (const u32*)bkt;
        u32* bg = (u32*)(bucket_g + (size_t)g * NPn * CAP);
        for (int i = t; i < nw; i += 512) bg[i] = bw[i];
    }
    __syncthreads();

    // ---- pass D: aggregate ------------------------------------------------
    const int w = t >> 6, l = t & 63;
    for (int n = w; n < NPn; n += 8) {
        int cnt = __builtin_amdgcn_readfirstlane(min(cin[n], CAP));
        int bv = (l < cnt) ? (int)bkt[n * CAP + l] : 0;
        float ax = 0.f, ay = 0.f;
        int i = 0;
        for (; i + 2 <= cnt; i += 2) {
            int s0 = __builtin_amdgcn_readlane(bv, i);
            int s1 = __builtin_amdgcn_readlane(bv, i + 1);
            float2 v0 = *(const float2*)&feat[s0 * 128 + 2 * l];
            float2 v1 = *(const float2*)&feat[s1 * 128 + 2 * l];
            ax += v0.x; ay += v0.y; ax += v1.x; ay += v1.y;
        }
        if (i < cnt) {
            int s0 = __builtin_amdgcn_readlane(bv, i);
            float2 v0 = *(const float2*)&feat[s0 * 128 + 2 * l];
            ax += v0.x; ay += v0.y;
        }
        float sc = rsqrtf((float)max(cnt, 1));
        *(float2*)&agg[((size_t)(g * NPn + n)) * D + 2 * l] = make_float2(ax * sc, ay * sc);
    }
}

// ---------------------------------------------------------------------------
// out = res + relu(agg @ W + b); epilogue also emits t[n] = dot(out[n],Ws)*scl[n].
__global__ __launch_bounds__(256) void k_gemm(
    const float* __restrict__ A, const float* __restrict__ Wm,
    const float* __restrict__ bias, const float* __restrict__ res,
    const float* __restrict__ Wsv, const float* __restrict__ sclg,
    float* __restrict__ outp, float* __restrict__ tbuf)
{
    __shared__ float4 At4[32 * 33];   // [perm(r/4)][kl]  rows of A (transposed)
    __shared__ float4 Wt4[32 * 33];   // [perm(c/4)][kl]
    __shared__ float  Wsl[128];
    __shared__ float  part[128 * 17];
    const int t  = threadIdx.x;
    const int tr = t >> 4;            // 0..15 : rows 8tr..8tr+7
    const int tc = t & 15;            // 0..15 : cols 8tc..8tc+7
    const int cb = tc * 8;
    const int lb = ((blockIdx.x & 7) * (gridDim.x >> 3)) + (blockIdx.x >> 3);
    const size_t r0 = (size_t)lb * 128;

    if (t < 128) Wsl[t] = Wsv[t];

    float acc[8][8];
#pragma unroll
    for (int i = 0; i < 8; ++i)
#pragma unroll
        for (int j = 0; j < 8; ++j) acc[i][j] = 0.f;

    for (int ph = 0; ph < 4; ++ph) {
        __syncthreads();
#pragma unroll
        for (int s2 = 0; s2 < 4; ++s2) {
            int idx = t + 256 * s2;
            int r  = idx >> 3;        // 0..127
            int kc = idx & 7;         // 0..7
            float4 v = *(const float4*)&A[(r0 + r) * D + ph * 32 + kc * 4];
            int r4 = r >> 2, lane = r & 3;
            int prow = (r4 >> 1) | ((r4 & 1) << 4);
            float* base = (float*)&At4[prow * 33 + kc * 4];
            base[0  + lane] = v.x;
            base[4  + lane] = v.y;
            base[8  + lane] = v.z;
            base[12 + lane] = v.w;
        }
#pragma unroll
        for (int s2 = 0; s2 < 4; ++s2) {
            int idx = t + 256 * s2;
            int wr  = idx >> 5;       // 0..31 (k)
            int wc4 = idx & 31;       // col quad
            float4 v = *(const float4*)&Wm[(size_t)(ph * 32 + wr) * D + wc4 * 4];
            int pcol = (wc4 >> 1) | ((wc4 & 1) << 4);
            Wt4[pcol * 33 + wr] = v;
        }
        __syncthreads();
#pragma unroll 4
        for (int kl = 0; kl < 32; ++kl) {
            float4 a0 = At4[tr * 33 + kl];
            float4 a1 = At4[(tr + 16) * 33 + kl];
            float4 w0 = Wt4[tc * 33 + kl];
            float4 w1 = Wt4[(tc + 16) * 33 + kl];
            float av[8] = {a0.x, a0.y, a0.z, a0.w, a1.x, a1.y, a1.z, a1.w};
            float wv[8] = {w0.x, w0.y, w0.z, w0.w, w1.x, w1.y, w1.z, w1.w};
#pragma unroll
            for (int i = 0; i < 8; ++i)
#pragma unroll
                for (int j = 0; j < 8; ++j)
                    acc[i][j] += av[i] * wv[j];
        }
    }
    __syncthreads();
    float bv[8];
#pragma unroll
    for (int j = 0; j < 8; ++j) bv[j] = bias[cb + j];
#pragma unroll
    for (int i = 0; i < 8; ++i) {
        size_t row = r0 + tr * 8 + i;
        float4 rA = *(const float4*)&res[row * D + cb];
        float4 rB = *(const float4*)&res[row * D + cb + 4];
        float o0 = rA.x + fmaxf(acc[i][0] + bv[0], 0.f);
        float o1 = rA.y + fmaxf(acc[i][1] + bv[1], 0.f);
        float o2 = rA.z + fmaxf(acc[i][2] + bv[2], 0.f);
        float o3 = rA.w + fmaxf(acc[i][3] + bv[3], 0.f);
        float o4 = rB.x + fmaxf(acc[i][4] + bv[4], 0.f);
        float o5 = rB.y + fmaxf(acc[i][5] + bv[5], 0.f);
        float o6 = rB.z + fmaxf(acc[i][6] + bv[6], 0.f);
        float o7 = rB.w + fmaxf(acc[i][7] + bv[7], 0.f);
        *(float4*)&outp[row * D + cb]     = make_float4(o0, o1, o2, o3);
        *(float4*)&outp[row * D + cb + 4] = make_float4(o4, o5, o6, o7);
        float p = o0 * Wsl[cb + 0] + o1 * Wsl[cb + 1] + o2 * Wsl[cb + 2] + o3 * Wsl[cb + 3]
                + o4 * Wsl[cb + 4] + o5 * Wsl[cb + 5] + o6 * Wsl[cb + 6] + o7 * Wsl[cb + 7];
        part[(tr * 8 + i) * 17 + tc] = p;
    }
    __syncthreads();
    if (t < 128) {
        float s = 0.f;
#pragma unroll
        for (int j = 0; j < 16; ++j) s += part[t * 17 + j];
        size_t n = r0 + t;
        tbuf[n] = s * sclg[n];
    }
}

// ---------------------------------------------------------------------------
// Per-graph pooling: score via pushed-through scalar GraphConv, exact top-k by
// rank counting, dis/com permutations, edge remap. Bucket entries are LOCAL ids.
template<int NPn, int K, bool REMAP>
__global__ __launch_bounds__(NPn) void k_pool(
    const float* __restrict__ tbuf, const u16* __restrict__ bucket,
    const int* __restrict__ cnt_in, const float* __restrict__ bsv,
    const int* __restrict__ srcE, const int* __restrict__ dstE,
    float* __restrict__ score_out, float* __restrict__ gate_out,
    int* __restrict__ perm_dis, int* __restrict__ perm_com,
    int* __restrict__ src_next, int* __restrict__ dst_next)
{
    __shared__ float sc[NPn];
    __shared__ int   pf[NPn];
    __shared__ int   lid[NPn];
    const int g = ((blockIdx.x & 7) << 5) | (blockIdx.x >> 3);
    const int t = threadIdx.x;
    const int n = g * NPn + t;

    int cnt = cnt_in[n]; if (cnt > CAP) cnt = CAP;
    const u16* bk = bucket + (size_t)n * CAP;
    float a = 0.f;
    int i = 0;
    for (; i + 2 <= cnt; i += 2) {
        float v0 = tbuf[g * NPn + bk[i]];
        float v1 = tbuf[g * NPn + bk[i + 1]];
        a += v0; a += v1;
    }
    if (i < cnt) a += tbuf[g * NPn + bk[i]];
    float my = a * rsqrtf((float)max(cnt, 1)) + bsv[0];
    score_out[n] = my;
    gate_out[n]  = tanhf(my);
    sc[t] = my;
    __syncthreads();

    int rank = 0;
    for (int j = 0; j < NPn; ++j) {
        float v = sc[j];
        rank += (int)((v > my) || (v == my && j < t));
    }
    const int kept = (rank < K) ? 1 : 0;
    pf[t] = kept;
    __syncthreads();
    int val = kept;
    for (int off = 1; off < NPn; off <<= 1) {
        int add = (t >= off) ? pf[t - off] : 0;
        __syncthreads();
        val += add;
        pf[t] = val;
        __syncthreads();
    }
    int excl = val - kept;
    if (kept) { lid[t] = excl;  perm_dis[g * K + excl] = n; }
    else      { lid[t] = -1;    perm_com[g * (NPn - K) + (t - excl)] = n; }
    __syncthreads();

    if (REMAP) {
        for (int e = g * EPG + t; e < (g + 1) * EPG; e += NPn) {
            int s = srcE[e];
            int ns = -1, nd = -1;
            if (s >= 0) {
                int ls  = lid[s - g * NPn];
                int ld2 = lid[dstE[e] - g * NPn];
                if (ls >= 0 && ld2 >= 0) { ns = g * K + ls; nd = g * K + ld2; }
            }
            src_next[e] = ns;
            dst_next[e] = nd;
        }
    }
}

// ---------------------------------------------------------------------------
__global__ __launch_bounds__(128) void k_gather(
    const float* __restrict__ x, const float* __restrict__ gate,
    const int* __restrict__ perm, float* __restrict__ outf)
{
    int i = blockIdx.x, t = threadIdx.x;
    int old = perm[i];
    outf[(size_t)i * D + t] = x[(size_t)old * D + t] * gate[old];
}

__global__ __launch_bounds__(128) void k_readout(
    const float* __restrict__ x, const float* __restrict__ gate,
    const int* __restrict__ perm_dis, const int* __restrict__ perm_com,
    int kcnt, float* __restrict__ hg, float* __restrict__ hgc,
    float* __restrict__ copy_com)
{
    int b = blockIdx.x, t = threadIdx.x;
    int com = (b >= NG) ? 1 : 0;
    int g = com ? b - NG : b;
    const int* perm = (com ? perm_com : perm_dis) + (size_t)g * kcnt;
    float sm = 0.f, mx = -INFINITY;
    int r = 0;
    for (; r + 4 <= kcnt; r += 4) {   // 4 rows in flight
        int o0 = perm[r], o1 = perm[r + 1], o2 = perm[r + 2], o3 = perm[r + 3];
        float v0 = x[(size_t)o0 * D + t] * gate[o0];
        float v1 = x[(size_t)o1 * D + t] * gate[o1];
        float v2 = x[(size_t)o2 * D + t] * gate[o2];
        float v3 = x[(size_t)o3 * D + t] * gate[o3];
        sm += v0; mx = fmaxf(mx, v0);
        sm += v1; mx = fmaxf(mx, v1);
        sm += v2; mx = fmaxf(mx, v2);
        sm += v3; mx = fmaxf(mx, v3);
    }
    for (; r < kcnt; ++r) {
        int o0 = perm[r];
        float v = x[(size_t)o0 * D + t] * gate[o0];
        sm += v; mx = fmaxf(mx, v);
    }
    float mean = sm * (1.f / (float)kcnt);
    float* dstp = com ? hgc : hg;
    dstp[(size_t)g * 256 + t]       += mean;
    dstp[(size_t)g * 256 + 128 + t] += mx;
    if (com && copy_com) {
        copy_com[(size_t)g * 256 + t]       = mean;
        copy_com[(size_t)g * 256 + 128 + t] = mx;
    }
}

// ---------------------------------------------------------------------------
__global__ __launch_bounds__(256) void k_node_mlp(
    const float* __restrict__ X,
    const float* __restrict__ W0, const float* __restrict__ b0,
    const float* __restrict__ W1, const float* __restrict__ b1,
    const float* __restrict__ W2, const float* __restrict__ b2,
    float* __restrict__ outp)
{
    __shared__ float xs[16 * 132];
    __shared__ float w0[128 * 64];
    __shared__ float h0[16 * 65];
    __shared__ float w1[64 * 32];
    __shared__ float h1[16 * 33];
    __shared__ float w2[32 * 10];
    int t = threadIdx.x;
    int r0 = blockIdx.x * 16;
    for (int i = t; i < 128 * 64; i += 256) w0[i] = W0[i];
    for (int i = t; i < 64 * 32;  i += 256) w1[i] = W1[i];
    for (int i = t; i < 320;      i += 256) w2[i] = W2[i];
    for (int i = t; i < 16 * 128; i += 256)
        xs[(i >> 7) * 132 + (i & 127)] = X[(size_t)(r0 + (i >> 7)) * D + (i & 127)];
    __syncthreads();
    {
        int r = t >> 4, c = (t & 15) * 4;
        float a0 = b0[c], a1 = b0[c + 1], a2 = b0[c + 2], a3 = b0[c + 3];
        const float* xr = &xs[r * 132];
        for (int k = 0; k < 128; ++k) {
            float xv = xr[k];
            float4 w = *(const float4*)&w0[k * 64 + c];
            a0 += xv * w.x; a1 += xv * w.y; a2 += xv * w.z; a3 += xv * w.w;
        }
        float* hr = &h0[r * 65 + c];
        hr[0] = fmaxf(a0, 0.f); hr[1] = fmaxf(a1, 0.f); hr[2] = fmaxf(a2, 0.f); hr[3] = fmaxf(a3, 0.f);
    }
    __syncthreads();
    {
        int r = t >> 4, c = (t & 15) * 2;
        float a0 = b1[c], a1 = b1[c + 1];
        const float* hr = &h0[r * 65];
        for (int k = 0; k < 64; ++k) {
            float xv = hr[k];
            a0 += xv * w1[k * 32 + c];
            a1 += xv * w1[k * 32 + c + 1];
        }
        h1[r * 33 + c]     = fmaxf(a0, 0.f);
        h1[r * 33 + c + 1] = fmaxf(a1, 0.f);
    }
    __syncthreads();
    if (t < 160) {
        int r = t / 10, c = t % 10;
        float a = b2[c];
        const float* hr = &h1[r * 33];
        for (int k = 0; k < 32; ++k) a += hr[k] * w2[k * 10 + c];
        outp[(size_t)(r0 + r) * 10 + c] = a;
    }
}

// ---------------------------------------------------------------------------
// scores/scores_com MLP. 128 blocks x 4 rows (was 16 blocks x 32 rows — 0.65%
// occupancy, 54 µs latency chain). Per-(row,col) k-order unchanged -> bit-identical.
__global__ __launch_bounds__(256) void k_graph_mlp(
    const float* __restrict__ hg, const float* __restrict__ hgc,
    const float* __restrict__ Wg0, const float* __restrict__ bg0,
    const float* __restrict__ Wg1, const float* __restrict__ bg1,
    const float* __restrict__ Wg2, const float* __restrict__ bg2,
    float* __restrict__ outp)
{
    __shared__ float xs[4][260];
    __shared__ float h0[4][132];
    __shared__ float h1[4][68];
    const int t = threadIdx.x;
    const int row0 = blockIdx.x * 4;
    {   // stage 4 rows (256 float4, one per thread)
        int r = t >> 6, q = t & 63;
        int gr = row0 + r;
        const float* srcp = (gr < NG) ? &hg[(size_t)gr * 256] : &hgc[(size_t)(gr - NG) * 256];
        *(float4*)&xs[r][q * 4] = *(const float4*)&srcp[q * 4];
    }
    __syncthreads();
    {   // L0: 256 -> 128, relu; thread: col c, 2 rows
        int c = t & 127, rp = (t >> 7) * 2;
        float bb = bg0[c];
        float a0 = bb, a1 = bb;
        for (int k = 0; k < 256; ++k) {
            float w = Wg0[(size_t)k * 128 + c];     // coalesced, L2-resident
            a0 += xs[rp][k] * w;                    // LDS broadcast
            a1 += xs[rp + 1][k] * w;
        }
        h0[rp][c]     = fmaxf(a0, 0.f);
        h0[rp + 1][c] = fmaxf(a1, 0.f);
    }
    __syncthreads();
    {   // L1: 128 -> 64, relu; thread: row t>>6, col t&63
        int c = t & 63, r = t >> 6;
        float a = bg1[c];
        for (int k = 0; k < 128; ++k) a += h0[r][k] * Wg1[(size_t)k * 64 + c];
        h1[r][c] = fmaxf(a, 0.f);
    }
    __syncthreads();
    if (t < 40) {   // L2: 64 -> 10
        int r = t / 10, c = t % 10;
        float a = bg2[c];
        for (int k = 0; k < 64; ++k) a += h1[r][k] * Wg2[k * 10 + c];
        outp[(size_t)(row0 + r) * 10 + c] = a;
    }
}

// ---------------------------------------------------------------------------
__global__ __launch_bounds__(256) void k_smax_part(const float* __restrict__ sc, float* __restrict__ pmax) {
    __shared__ float red[256];
    int t = threadIdx.x;
    float m = -INFINITY;
    for (int i = blockIdx.x * 256 + t; i < N1; i += 64 * 256) m = fmaxf(m, sc[i]);
    red[t] = m; __syncthreads();
    for (int off = 128; off > 0; off >>= 1) {
        if (t < off) red[t] = fmaxf(red[t], red[t + off]);
        __syncthreads();
    }
    if (t == 0) pmax[blockIdx.x] = red[0];
}
__global__ __launch_bounds__(256) void k_smax_sum(const float* __restrict__ sc, const float* __restrict__ pmax,
                                                 float* __restrict__ psum) {
    __shared__ float red[256];
    int t = threadIdx.x;
    float gm = -INFINITY;
#pragma unroll
    for (int i = 0; i < 64; ++i) gm = fmaxf(gm, pmax[i]);
    float s = 0.f;
    for (int i = blockIdx.x * 256 + t; i < N1; i += 64 * 256) s += expf(sc[i] - gm);
    red[t] = s; __syncthreads();
    for (int off = 128; off > 0; off >>= 1) {
        if (t < off) red[t] += red[t + off];
        __syncthreads();
    }
    if (t == 0) psum[blockIdx.x] = red[0];
}
__global__ __launch_bounds__(256) void k_smax_out(const float* __restrict__ sc, const float* __restrict__ pmax,
                                                 const float* __restrict__ psum, float* __restrict__ outp) {
    int t = threadIdx.x;
    float gm = -INFINITY; float gs = 0.f;
#pragma unroll
    for (int i = 0; i < 64; ++i) { gm = fmaxf(gm, pmax[i]); gs += psum[i]; }
    int i = blockIdx.x * 256 + t;
    outp[i] = expf(sc[i] - gm) / gs;
}

// ---------------------------------------------------------------------------
extern "C" void kernel_launch(void* const* d_in, const int* in_sizes, int n_in,
                              void* d_out, int out_size, void* d_ws, size_t ws_size,
                              hipStream_t stream) {
    const float* feature = (const float*)d_in[0];
    const int*   src     = (const int*)d_in[1];
    const int*   dst     = (const int*)d_in[2];
    const float* W1  = (const float*)d_in[4];
    const float* b1  = (const float*)d_in[5];
    const float* W2  = (const float*)d_in[6];
    const float* b2  = (const float*)d_in[7];
    const float* W3  = (const float*)d_in[8];
    const float* b3  = (const float*)d_in[9];
    const float* Wsv = (const float*)d_in[10];
    const float* bsv = (const float*)d_in[11];
    const float* Wg0 = (const float*)d_in[12];
    const float* bg0 = (const float*)d_in[13];
    const float* Wg1 = (const float*)d_in[14];
    const float* bg1 = (const float*)d_in[15];
    const float* Wg2 = (const float*)d_in[16];
    const float* bg2 = (const float*)d_in[17];
    const float* Wp0 = (const float*)d_in[18];
    const float* bp0 = (const float*)d_in[19];
    const float* Wp1 = (const float*)d_in[20];
    const float* bp1 = (const float*)d_in[21];
    const float* Wp2 = (const float*)d_in[22];
    const float* bp2 = (const float*)d_in[23];

    float* out = (float*)d_out;
    float* o_scores    = out;            // [512][10]
    float* o_hg3com    = out + 5120;     // [256][256]
    float* o_nodepred  = out + 70656;    // [16384][10]
    float* o_nodescore = out + 234496;   // [65536]

    float* ws = (float*)d_ws;
    size_t off = 0;
    auto alloc_f = [&](size_t n) { float* p = ws + off; off += (n + 63) & ~(size_t)63; return p; };
    float* agg    = alloc_f(8388608);   // [65536][128]
    float* outbuf = alloc_f(8388608);
    float* f1d    = alloc_f(4194304);
    float* f2d    = alloc_f(2097152);
    u16*   bucket = (u16*)alloc_f(1572864);   // [65536][48] ushort
    int*   src2   = (int*)alloc_f(1048576);
    int*   dst2   = (int*)alloc_f(1048576);
    int*   src3   = (int*)alloc_f(1048576);
    int*   dst3   = (int*)alloc_f(1048576);
    int*   cnt_in = (int*)alloc_f(65536);
    float* sclg   = alloc_f(65536);
    float* tbuf   = alloc_f(65536);
    float* gate   = alloc_f(65536);
    float* score1 = alloc_f(65536);
    float* scoreX = alloc_f(65536);
    int*   perm_d = (int*)alloc_f(32768);
    int*   perm_c = (int*)alloc_f(32768);
    float* hg     = alloc_f(65536);
    float* hg_com = alloc_f(65536);
    float* pmax   = alloc_f(64);
    float* psum   = alloc_f(64);
    (void)ws_size; (void)in_sizes; (void)n_in; (void)out_size;

    hipMemsetAsync(hg, 0, 2 * 65536 * sizeof(float), stream);

    // =================== stage 1 (N=65536, np=256, k=128) ==================
    k_agg_build<256><<<NG, 512, 0, stream>>>(feature, src, dst, agg, bucket, cnt_in, sclg);
    k_gemm<<<65536 / 128, 256, 0, stream>>>(agg, W1, b1, feature, Wsv, sclg, outbuf, tbuf);
    k_pool<256, 128, true><<<NG, 256, 0, stream>>>(tbuf, bucket, cnt_in, bsv, src, dst,
                                                   score1, gate, perm_d, perm_c, src2, dst2);
    k_gather<<<NG * 128, 128, 0, stream>>>(outbuf, gate, perm_d, f1d);
    k_readout<<<2 * NG, 128, 0, stream>>>(outbuf, gate, perm_d, perm_c, 128, hg, hg_com, nullptr);

    // =================== stage 2 (N=32768, np=128, k=64) ===================
    k_agg_build<128><<<NG, 512, 0, stream>>>(f1d, src2, dst2, agg, bucket, cnt_in, sclg);
    k_gemm<<<32768 / 128, 256, 0, stream>>>(agg, W2, b2, f1d, Wsv, sclg, outbuf, tbuf);
    k_pool<128, 64, true><<<NG, 128, 0, stream>>>(tbuf, bucket, cnt_in, bsv, src2, dst2,
                                                  scoreX, gate, perm_d, perm_c, src3, dst3);
    k_gather<<<NG * 64, 128, 0, stream>>>(outbuf, gate, perm_d, f2d);
    k_readout<<<2 * NG, 128, 0, stream>>>(outbuf, gate, perm_d, perm_c, 64, hg, hg_com, nullptr);

    // =================== stage 3 (N=16384, np=64, k=32) ====================
    k_agg_build<64><<<NG, 512, 0, stream>>>(f2d, src3, dst3, agg, bucket, cnt_in, sclg);
    k_gemm<<<16384 / 128, 256, 0, stream>>>(agg, W3, b3, f2d, Wsv, sclg, outbuf, tbuf);
    k_pool<64, 32, false><<<NG, 64, 0, stream>>>(tbuf, bucket, cnt_in, bsv, nullptr, nullptr,
                                                 scoreX, gate, perm_d, perm_c, nullptr, nullptr);
    k_readout<<<2 * NG, 128, 0, stream>>>(outbuf, gate, perm_d, perm_c, 32, hg, hg_com, o_hg3com);

    // =================== heads =============================================
    k_node_mlp<<<16384 / 16, 256, 0, stream>>>(outbuf, Wp0, bp0, Wp1, bp1, Wp2, bp2, o_nodepred);
    k_graph_mlp<<<128, 256, 0, stream>>>(hg, hg_com, Wg0, bg0, Wg1, bg1, Wg2, bg2, o_scores);
    k_smax_part<<<64, 256, 0, stream>>>(score1, pmax);
    k_smax_sum<<<64, 256, 0, stream>>>(score1, pmax, psum);
    k_smax_out<<<N1 / 256, 256, 0, stream>>>(score1, pmax, psum, o_nodescore);
}

// Round 9
// 393.568 us; speedup vs baseline: 1.4894x; 1.0159x over previous
//
#include <hip/hip_runtime.h>
#include <math.h>

#define NG    256          // graphs
#define D     128          // feature dim
#define EPG   4096         // edge capacity per graph (constant across stages)
#define NEDGE (NG*EPG)     // 1048576
#define CAP   48           // incoming-edge bucket capacity per node (P(deg>48) ~ 6e-11)
#define N1    65536        // stage-1 node count

typedef unsigned short u16;
typedef unsigned int   u32;

// ---------------------------------------------------------------------------
// Fused per-graph build + aggregate, async-staged. One 512-thread block/graph:
//  entry:  issue RAW feature loads (reg-staged) + edge loads  — HBM latency
//          hides under pass A's LDS atomics (T14 async-STAGE split)
//  pass A: degree counts + incoming-edge bucket via LDS atomics
//  pass B: scl = rsqrt(max(deg_out,1)); dump cnt_in/scl
//  write:  feat = fx * scl (scale-on-write, same product as before)
//  pass D: per-wave node aggregation, 4-unrolled (4 ds_read_b64 in flight)
template<int NPn>
__global__ __launch_bounds__(512) void k_agg_build(
    const float* __restrict__ x, const int* __restrict__ srcE, const int* __restrict__ dstE,
    float* __restrict__ agg, u16* __restrict__ bucket_g,
    int* __restrict__ cnt_in_g, float* __restrict__ sclg)
{
    constexpr int NCH = NPn / 16;         // float4 chunks per thread (16 at NPn=256)
    __shared__ float feat[NPn * 128];     // 128 KB at NPn=256
    __shared__ u16   bkt[NPn * CAP];      // 24 KB at NPn=256
    __shared__ int   cin[NPn];
    __shared__ int   cout[NPn];
    __shared__ float scll[NPn];
    const int g = ((blockIdx.x & 7) << 5) | (blockIdx.x >> 3);  // graph g on XCD g/32
    const int t = threadIdx.x;

    // zero counters first (so the first barrier only waits on LDS, not loads)
    for (int i = t; i < NPn; i += 512) { cin[i] = 0; cout[i] = 0; }

    // ---- issue staging loads EARLY (raw features + this thread's 8 edges) --
    float4 fx[NCH];
    const float4* xsrc = (const float4*)(x + (size_t)g * NPn * 128);
#pragma unroll
    for (int c = 0; c < NCH; ++c) fx[c] = xsrc[c * 512 + t];
    int es[8], ed[8];
#pragma unroll
    for (int j = 0; j < 8; ++j) {
        es[j] = srcE[g * EPG + j * 512 + t];
        ed[j] = dstE[g * EPG + j * 512 + t];
    }
    __builtin_amdgcn_sched_barrier(0);    // keep the load issues above this point
    __syncthreads();

    // ---- pass A: count + bucket-fill via LDS atomics ----------------------
#pragma unroll
    for (int j = 0; j < 8; ++j) {
        int s = es[j];
        if (s >= 0) {
            int sl = s - g * NPn;
            int dl = ed[j] - g * NPn;
            atomicAdd(&cout[sl], 1);
            int pos = atomicAdd(&cin[dl], 1);
            if (pos < CAP) bkt[dl * CAP + pos] = (u16)sl;
        }
    }
    __syncthreads();

    // ---- pass B: scl + global dumps ---------------------------------------
    for (int i = t; i < NPn; i += 512) {
        cnt_in_g[g * NPn + i] = cin[i];
        float sc = rsqrtf((float)max(cout[i], 1));
        sclg[g * NPn + i] = sc;
        scll[i] = sc;
    }
    __syncthreads();

    // ---- write feat = fx * scl (scale-on-write) ---------------------------
#pragma unroll
    for (int c = 0; c < NCH; ++c) {
        int idx = c * 512 + t;
        float s = scll[idx >> 5];         // 32 float4 per row
        float4 v = fx[c];
        v.x *= s; v.y *= s; v.z *= s; v.w *= s;
        *(float4*)&feat[idx * 4] = v;
    }
    // dump bucket to global (coalesced u32 view) for k_pool
    {
        const int nw = NPn * CAP / 2;
        const u32* bw = (const u32*)bkt;
        u32* bg = (u32*)(bucket_g + (size_t)g * NPn * CAP);
        for (int i = t; i < nw; i += 512) bg[i] = bw[i];
    }
    __syncthreads();

    // ---- pass D: aggregate, 4-unrolled ------------------------------------
    const int w = t >> 6, l = t & 63;
    for (int n = w; n < NPn; n += 8) {
        int cnt = __builtin_amdgcn_readfirstlane(min(cin[n], CAP));
        int bv = (l < cnt) ? (int)bkt[n * CAP + l] : 0;
        float ax0 = 0.f, ay0 = 0.f, ax1 = 0.f, ay1 = 0.f;
        int i = 0;
        for (; i + 4 <= cnt; i += 4) {
            int s0 = __builtin_amdgcn_readlane(bv, i);
            int s1 = __builtin_amdgcn_readlane(bv, i + 1);
            int s2 = __builtin_amdgcn_readlane(bv, i + 2);
            int s3 = __builtin_amdgcn_readlane(bv, i + 3);
            float2 v0 = *(const float2*)&feat[s0 * 128 + 2 * l];
            float2 v1 = *(const float2*)&feat[s1 * 128 + 2 * l];
            float2 v2 = *(const float2*)&feat[s2 * 128 + 2 * l];
            float2 v3 = *(const float2*)&feat[s3 * 128 + 2 * l];
            ax0 += v0.x; ay0 += v0.y; ax0 += v1.x; ay0 += v1.y;
            ax1 += v2.x; ay1 += v2.y; ax1 += v3.x; ay1 += v3.y;
        }
        for (; i < cnt; ++i) {
            int s0 = __builtin_amdgcn_readlane(bv, i);
            float2 v0 = *(const float2*)&feat[s0 * 128 + 2 * l];
            ax0 += v0.x; ay0 += v0.y;
        }
        float sc = rsqrtf((float)max(cnt, 1));
        float ax = ax0 + ax1, ay = ay0 + ay1;
        *(float2*)&agg[((size_t)(g * NPn + n)) * D + 2 * l] = make_float2(ax * sc, ay * sc);
    }
}

// ---------------------------------------------------------------------------
// out = res + relu(agg @ W + b); epilogue also emits t[n] = dot(out[n],Ws)*scl[n].
__global__ __launch_bounds__(256) void k_gemm(
    const float* __restrict__ A, const float* __restrict__ Wm,
    const float* __restrict__ bias, const float* __restrict__ res,
    const float* __restrict__ Wsv, const float* __restrict__ sclg,
    float* __restrict__ outp, float* __restrict__ tbuf)
{
    __shared__ float4 At4[32 * 33];   // [perm(r/4)][kl]  rows of A (transposed)
    __shared__ float4 Wt4[32 * 33];   // [perm(c/4)][kl]
    __shared__ float  Wsl[128];
    __shared__ float  part[128 * 17];
    const int t  = threadIdx.x;
    const int tr = t >> 4;            // 0..15 : rows 8tr..8tr+7
    const int tc = t & 15;            // 0..15 : cols 8tc..8tc+7
    const int cb = tc * 8;
    const int lb = ((blockIdx.x & 7) * (gridDim.x >> 3)) + (blockIdx.x >> 3);
    const size_t r0 = (size_t)lb * 128;

    if (t < 128) Wsl[t] = Wsv[t];

    float acc[8][8];
#pragma unroll
    for (int i = 0; i < 8; ++i)
#pragma unroll
        for (int j = 0; j < 8; ++j) acc[i][j] = 0.f;

    for (int ph = 0; ph < 4; ++ph) {
        __syncthreads();
#pragma unroll
        for (int s2 = 0; s2 < 4; ++s2) {
            int idx = t + 256 * s2;
            int r  = idx >> 3;        // 0..127
            int kc = idx & 7;         // 0..7
            float4 v = *(const float4*)&A[(r0 + r) * D + ph * 32 + kc * 4];
            int r4 = r >> 2, lane = r & 3;
            int prow = (r4 >> 1) | ((r4 & 1) << 4);
            float* base = (float*)&At4[prow * 33 + kc * 4];
            base[0  + lane] = v.x;
            base[4  + lane] = v.y;
            base[8  + lane] = v.z;
            base[12 + lane] = v.w;
        }
#pragma unroll
        for (int s2 = 0; s2 < 4; ++s2) {
            int idx = t + 256 * s2;
            int wr  = idx >> 5;       // 0..31 (k)
            int wc4 = idx & 31;       // col quad
            float4 v = *(const float4*)&Wm[(size_t)(ph * 32 + wr) * D + wc4 * 4];
            int pcol = (wc4 >> 1) | ((wc4 & 1) << 4);
            Wt4[pcol * 33 + wr] = v;
        }
        __syncthreads();
#pragma unroll 4
        for (int kl = 0; kl < 32; ++kl) {
            float4 a0 = At4[tr * 33 + kl];
            float4 a1 = At4[(tr + 16) * 33 + kl];
            float4 w0 = Wt4[tc * 33 + kl];
            float4 w1 = Wt4[(tc + 16) * 33 + kl];
            float av[8] = {a0.x, a0.y, a0.z, a0.w, a1.x, a1.y, a1.z, a1.w};
            float wv[8] = {w0.x, w0.y, w0.z, w0.w, w1.x, w1.y, w1.z, w1.w};
#pragma unroll
            for (int i = 0; i < 8; ++i)
#pragma unroll
                for (int j = 0; j < 8; ++j)
                    acc[i][j] += av[i] * wv[j];
        }
    }
    __syncthreads();
    float bv[8];
#pragma unroll
    for (int j = 0; j < 8; ++j) bv[j] = bias[cb + j];
#pragma unroll
    for (int i = 0; i < 8; ++i) {
        size_t row = r0 + tr * 8 + i;
        float4 rA = *(const float4*)&res[row * D + cb];
        float4 rB = *(const float4*)&res[row * D + cb + 4];
        float o0 = rA.x + fmaxf(acc[i][0] + bv[0], 0.f);
        float o1 = rA.y + fmaxf(acc[i][1] + bv[1], 0.f);
        float o2 = rA.z + fmaxf(acc[i][2] + bv[2], 0.f);
        float o3 = rA.w + fmaxf(acc[i][3] + bv[3], 0.f);
        float o4 = rB.x + fmaxf(acc[i][4] + bv[4], 0.f);
        float o5 = rB.y + fmaxf(acc[i][5] + bv[5], 0.f);
        float o6 = rB.z + fmaxf(acc[i][6] + bv[6], 0.f);
        float o7 = rB.w + fmaxf(acc[i][7] + bv[7], 0.f);
        *(float4*)&outp[row * D + cb]     = make_float4(o0, o1, o2, o3);
        *(float4*)&outp[row * D + cb + 4] = make_float4(o4, o5, o6, o7);
        float p = o0 * Wsl[cb + 0] + o1 * Wsl[cb + 1] + o2 * Wsl[cb + 2] + o3 * Wsl[cb + 3]
                + o4 * Wsl[cb + 4] + o5 * Wsl[cb + 5] + o6 * Wsl[cb + 6] + o7 * Wsl[cb + 7];
        part[(tr * 8 + i) * 17 + tc] = p;
    }
    __syncthreads();
    if (t < 128) {
        float s = 0.f;
#pragma unroll
        for (int j = 0; j < 16; ++j) s += part[t * 17 + j];
        size_t n = r0 + t;
        tbuf[n] = s * sclg[n];
    }
}

// ---------------------------------------------------------------------------
// Per-graph pooling: score via pushed-through scalar GraphConv, exact top-k by
// rank counting, dis/com permutations, edge remap. Bucket entries are LOCAL ids.
template<int NPn, int K, bool REMAP>
__global__ __launch_bounds__(NPn) void k_pool(
    const float* __restrict__ tbuf, const u16* __restrict__ bucket,
    const int* __restrict__ cnt_in, const float* __restrict__ bsv,
    const int* __restrict__ srcE, const int* __restrict__ dstE,
    float* __restrict__ score_out, float* __restrict__ gate_out,
    int* __restrict__ perm_dis, int* __restrict__ perm_com,
    int* __restrict__ src_next, int* __restrict__ dst_next)
{
    __shared__ float sc[NPn];
    __shared__ int   pf[NPn];
    __shared__ int   lid[NPn];
    const int g = ((blockIdx.x & 7) << 5) | (blockIdx.x >> 3);
    const int t = threadIdx.x;
    const int n = g * NPn + t;

    int cnt = cnt_in[n]; if (cnt > CAP) cnt = CAP;
    const u16* bk = bucket + (size_t)n * CAP;
    float a = 0.f;
    int i = 0;
    for (; i + 2 <= cnt; i += 2) {
        float v0 = tbuf[g * NPn + bk[i]];
        float v1 = tbuf[g * NPn + bk[i + 1]];
        a += v0; a += v1;
    }
    if (i < cnt) a += tbuf[g * NPn + bk[i]];
    float my = a * rsqrtf((float)max(cnt, 1)) + bsv[0];
    score_out[n] = my;
    gate_out[n]  = tanhf(my);
    sc[t] = my;
    __syncthreads();

    int rank = 0;
    for (int j = 0; j < NPn; ++j) {
        float v = sc[j];
        rank += (int)((v > my) || (v == my && j < t));
    }
    const int kept = (rank < K) ? 1 : 0;
    pf[t] = kept;
    __syncthreads();
    int val = kept;
    for (int off = 1; off < NPn; off <<= 1) {
        int add = (t >= off) ? pf[t - off] : 0;
        __syncthreads();
        val += add;
        pf[t] = val;
        __syncthreads();
    }
    int excl = val - kept;
    if (kept) { lid[t] = excl;  perm_dis[g * K + excl] = n; }
    else      { lid[t] = -1;    perm_com[g * (NPn - K) + (t - excl)] = n; }
    __syncthreads();

    if (REMAP) {
        for (int e = g * EPG + t; e < (g + 1) * EPG; e += NPn) {
            int s = srcE[e];
            int ns = -1, nd = -1;
            if (s >= 0) {
                int ls  = lid[s - g * NPn];
                int ld2 = lid[dstE[e] - g * NPn];
                if (ls >= 0 && ld2 >= 0) { ns = g * K + ls; nd = g * K + ld2; }
            }
            src_next[e] = ns;
            dst_next[e] = nd;
        }
    }
}

// ---------------------------------------------------------------------------
__global__ __launch_bounds__(128) void k_gather(
    const float* __restrict__ x, const float* __restrict__ gate,
    const int* __restrict__ perm, float* __restrict__ outf)
{
    int i = blockIdx.x, t = threadIdx.x;
    int old = perm[i];
    outf[(size_t)i * D + t] = x[(size_t)old * D + t] * gate[old];
}

__global__ __launch_bounds__(128) void k_readout(
    const float* __restrict__ x, const float* __restrict__ gate,
    const int* __restrict__ perm_dis, const int* __restrict__ perm_com,
    int kcnt, float* __restrict__ hg, float* __restrict__ hgc,
    float* __restrict__ copy_com)
{
    int b = blockIdx.x, t = threadIdx.x;
    int com = (b >= NG) ? 1 : 0;
    int g = com ? b - NG : b;
    const int* perm = (com ? perm_com : perm_dis) + (size_t)g * kcnt;
    float sm = 0.f, mx = -INFINITY;
    int r = 0;
    for (; r + 4 <= kcnt; r += 4) {   // 4 rows in flight
        int o0 = perm[r], o1 = perm[r + 1], o2 = perm[r + 2], o3 = perm[r + 3];
        float v0 = x[(size_t)o0 * D + t] * gate[o0];
        float v1 = x[(size_t)o1 * D + t] * gate[o1];
        float v2 = x[(size_t)o2 * D + t] * gate[o2];
        float v3 = x[(size_t)o3 * D + t] * gate[o3];
        sm += v0; mx = fmaxf(mx, v0);
        sm += v1; mx = fmaxf(mx, v1);
        sm += v2; mx = fmaxf(mx, v2);
        sm += v3; mx = fmaxf(mx, v3);
    }
    for (; r < kcnt; ++r) {
        int o0 = perm[r];
        float v = x[(size_t)o0 * D + t] * gate[o0];
        sm += v; mx = fmaxf(mx, v);
    }
    float mean = sm * (1.f / (float)kcnt);
    float* dstp = com ? hgc : hg;
    dstp[(size_t)g * 256 + t]       += mean;
    dstp[(size_t)g * 256 + 128 + t] += mx;
    if (com && copy_com) {
        copy_com[(size_t)g * 256 + t]       = mean;
        copy_com[(size_t)g * 256 + 128 + t] = mx;
    }
}

// ---------------------------------------------------------------------------
__global__ __launch_bounds__(256) void k_node_mlp(
    const float* __restrict__ X,
    const float* __restrict__ W0, const float* __restrict__ b0,
    const float* __restrict__ W1, const float* __restrict__ b1,
    const float* __restrict__ W2, const float* __restrict__ b2,
    float* __restrict__ outp)
{
    __shared__ float xs[16 * 132];
    __shared__ float w0[128 * 64];
    __shared__ float h0[16 * 65];
    __shared__ float w1[64 * 32];
    __shared__ float h1[16 * 33];
    __shared__ float w2[32 * 10];
    int t = threadIdx.x;
    int r0 = blockIdx.x * 16;
    for (int i = t; i < 128 * 64; i += 256) w0[i] = W0[i];
    for (int i = t; i < 64 * 32;  i += 256) w1[i] = W1[i];
    for (int i = t; i < 320;      i += 256) w2[i] = W2[i];
    for (int i = t; i < 16 * 128; i += 256)
        xs[(i >> 7) * 132 + (i & 127)] = X[(size_t)(r0 + (i >> 7)) * D + (i & 127)];
    __syncthreads();
    {
        int r = t >> 4, c = (t & 15) * 4;
        float a0 = b0[c], a1 = b0[c + 1], a2 = b0[c + 2], a3 = b0[c + 3];
        const float* xr = &xs[r * 132];
        for (int k = 0; k < 128; ++k) {
            float xv = xr[k];
            float4 w = *(const float4*)&w0[k * 64 + c];
            a0 += xv * w.x; a1 += xv * w.y; a2 += xv * w.z; a3 += xv * w.w;
        }
        float* hr = &h0[r * 65 + c];
        hr[0] = fmaxf(a0, 0.f); hr[1] = fmaxf(a1, 0.f); hr[2] = fmaxf(a2, 0.f); hr[3] = fmaxf(a3, 0.f);
    }
    __syncthreads();
    {
        int r = t >> 4, c = (t & 15) * 2;
        float a0 = b1[c], a1 = b1[c + 1];
        const float* hr = &h0[r * 65];
        for (int k = 0; k < 64; ++k) {
            float xv = hr[k];
            a0 += xv * w1[k * 32 + c];
            a1 += xv * w1[k * 32 + c + 1];
        }
        h1[r * 33 + c]     = fmaxf(a0, 0.f);
        h1[r * 33 + c + 1] = fmaxf(a1, 0.f);
    }
    __syncthreads();
    if (t < 160) {
        int r = t / 10, c = t % 10;
        float a = b2[c];
        const float* hr = &h1[r * 33];
        for (int k = 0; k < 32; ++k) a += hr[k] * w2[k * 10 + c];
        outp[(size_t)(r0 + r) * 10 + c] = a;
    }
}

// ---------------------------------------------------------------------------
// scores/scores_com MLP. 128 blocks x 4 rows; per-(row,col) k-order matches
// the original -> bit-identical o_scores.
__global__ __launch_bounds__(256) void k_graph_mlp(
    const float* __restrict__ hg, const float* __restrict__ hgc,
    const float* __restrict__ Wg0, const float* __restrict__ bg0,
    const float* __restrict__ Wg1, const float* __restrict__ bg1,
    const float* __restrict__ Wg2, const float* __restrict__ bg2,
    float* __restrict__ outp)
{
    __shared__ float xs[4][260];
    __shared__ float h0[4][132];
    __shared__ float h1[4][68];
    const int t = threadIdx.x;
    const int row0 = blockIdx.x * 4;
    {   // stage 4 rows (256 float4, one per thread)
        int r = t >> 6, q = t & 63;
        int gr = row0 + r;
        const float* srcp = (gr < NG) ? &hg[(size_t)gr * 256] : &hgc[(size_t)(gr - NG) * 256];
        *(float4*)&xs[r][q * 4] = *(const float4*)&srcp[q * 4];
    }
    __syncthreads();
    {   // L0: 256 -> 128, relu; thread: col c, 2 rows
        int c = t & 127, rp = (t >> 7) * 2;
        float bb = bg0[c];
        float a0 = bb, a1 = bb;
        for (int k = 0; k < 256; ++k) {
            float w = Wg0[(size_t)k * 128 + c];     // coalesced, L2-resident
            a0 += xs[rp][k] * w;                    // LDS broadcast
            a1 += xs[rp + 1][k] * w;
        }
        h0[rp][c]     = fmaxf(a0, 0.f);
        h0[rp + 1][c] = fmaxf(a1, 0.f);
    }
    __syncthreads();
    {   // L1: 128 -> 64, relu; thread: row t>>6, col t&63
        int c = t & 63, r = t >> 6;
        float a = bg1[c];
        for (int k = 0; k < 128; ++k) a += h0[r][k] * Wg1[(size_t)k * 64 + c];
        h1[r][c] = fmaxf(a, 0.f);
    }
    __syncthreads();
    if (t < 40) {   // L2: 64 -> 10
        int r = t / 10, c = t % 10;
        float a = bg2[c];
        for (int k = 0; k < 64; ++k) a += h1[r][k] * Wg2[k * 10 + c];
        outp[(size_t)(row0 + r) * 10 + c] = a;
    }
}

// ---------------------------------------------------------------------------
__global__ __launch_bounds__(256) void k_smax_part(const float* __restrict__ sc, float* __restrict__ pmax) {
    __shared__ float red[256];
    int t = threadIdx.x;
    float m = -INFINITY;
    for (int i = blockIdx.x * 256 + t; i < N1; i += 64 * 256) m = fmaxf(m, sc[i]);
    red[t] = m; __syncthreads();
    for (int off = 128; off > 0; off >>= 1) {
        if (t < off) red[t] = fmaxf(red[t], red[t + off]);
        __syncthreads();
    }
    if (t == 0) pmax[blockIdx.x] = red[0];
}
__global__ __launch_bounds__(256) void k_smax_sum(const float* __restrict__ sc, const float* __restrict__ pmax,
                                                 float* __restrict__ psum) {
    __shared__ float red[256];
    int t = threadIdx.x;
    float gm = -INFINITY;
#pragma unroll
    for (int i = 0; i < 64; ++i) gm = fmaxf(gm, pmax[i]);
    float s = 0.f;
    for (int i = blockIdx.x * 256 + t; i < N1; i += 64 * 256) s += expf(sc[i] - gm);
    red[t] = s; __syncthreads();
    for (int off = 128; off > 0; off >>= 1) {
        if (t < off) red[t] += red[t + off];
        __syncthreads();
    }
    if (t == 0) psum[blockIdx.x] = red[0];
}
__global__ __launch_bounds__(256) void k_smax_out(const float* __restrict__ sc, const float* __restrict__ pmax,
                                                 const float* __restrict__ psum, float* __restrict__ outp) {
    int t = threadIdx.x;
    float gm = -INFINITY; float gs = 0.f;
#pragma unroll
    for (int i = 0; i < 64; ++i) { gm = fmaxf(gm, pmax[i]); gs += psum[i]; }
    int i = blockIdx.x * 256 + t;
    outp[i] = expf(sc[i] - gm) / gs;
}

// ---------------------------------------------------------------------------
extern "C" void kernel_launch(void* const* d_in, const int* in_sizes, int n_in,
                              void* d_out, int out_size, void* d_ws, size_t ws_size,
                              hipStream_t stream) {
    const float* feature = (const float*)d_in[0];
    const int*   src     = (const int*)d_in[1];
    const int*   dst     = (const int*)d_in[2];
    const float* W1  = (const float*)d_in[4];
    const float* b1  = (const float*)d_in[5];
    const float* W2  = (const float*)d_in[6];
    const float* b2  = (const float*)d_in[7];
    const float* W3  = (const float*)d_in[8];
    const float* b3  = (const float*)d_in[9];
    const float* Wsv = (const float*)d_in[10];
    const float* bsv = (const float*)d_in[11];
    const float* Wg0 = (const float*)d_in[12];
    const float* bg0 = (const float*)d_in[13];
    const float* Wg1 = (const float*)d_in[14];
    const float* bg1 = (const float*)d_in[15];
    const float* Wg2 = (const float*)d_in[16];
    const float* bg2 = (const float*)d_in[17];
    const float* Wp0 = (const float*)d_in[18];
    const float* bp0 = (const float*)d_in[19];
    const float* Wp1 = (const float*)d_in[20];
    const float* bp1 = (const float*)d_in[21];
    const float* Wp2 = (const float*)d_in[22];
    const float* bp2 = (const float*)d_in[23];

    float* out = (float*)d_out;
    float* o_scores    = out;            // [512][10]
    float* o_hg3com    = out + 5120;     // [256][256]
    float* o_nodepred  = out + 70656;    // [16384][10]
    float* o_nodescore = out + 234496;   // [65536]

    float* ws = (float*)d_ws;
    size_t off = 0;
    auto alloc_f = [&](size_t n) { float* p = ws + off; off += (n + 63) & ~(size_t)63; return p; };
    float* agg    = alloc_f(8388608);   // [65536][128]
    float* outbuf = alloc_f(8388608);
    float* f1d    = alloc_f(4194304);
    float* f2d    = alloc_f(2097152);
    u16*   bucket = (u16*)alloc_f(1572864);   // [65536][48] ushort
    int*   src2   = (int*)alloc_f(1048576);
    int*   dst2   = (int*)alloc_f(1048576);
    int*   src3   = (int*)alloc_f(1048576);
    int*   dst3   = (int*)alloc_f(1048576);
    int*   cnt_in = (int*)alloc_f(65536);
    float* sclg   = alloc_f(65536);
    float* tbuf   = alloc_f(65536);
    float* gate   = alloc_f(65536);
    float* score1 = alloc_f(65536);
    float* scoreX = alloc_f(65536);
    int*   perm_d = (int*)alloc_f(32768);
    int*   perm_c = (int*)alloc_f(32768);
    float* hg     = alloc_f(65536);
    float* hg_com = alloc_f(65536);
    float* pmax   = alloc_f(64);
    float* psum   = alloc_f(64);
    (void)ws_size; (void)in_sizes; (void)n_in; (void)out_size;

    hipMemsetAsync(hg, 0, 2 * 65536 * sizeof(float), stream);

    // =================== stage 1 (N=65536, np=256, k=128) ==================
    k_agg_build<256><<<NG, 512, 0, stream>>>(feature, src, dst, agg, bucket, cnt_in, sclg);
    k_gemm<<<65536 / 128, 256, 0, stream>>>(agg, W1, b1, feature, Wsv, sclg, outbuf, tbuf);
    k_pool<256, 128, true><<<NG, 256, 0, stream>>>(tbuf, bucket, cnt_in, bsv, src, dst,
                                                   score1, gate, perm_d, perm_c, src2, dst2);
    k_gather<<<NG * 128, 128, 0, stream>>>(outbuf, gate, perm_d, f1d);
    k_readout<<<2 * NG, 128, 0, stream>>>(outbuf, gate, perm_d, perm_c, 128, hg, hg_com, nullptr);

    // =================== stage 2 (N=32768, np=128, k=64) ===================
    k_agg_build<128><<<NG, 512, 0, stream>>>(f1d, src2, dst2, agg, bucket, cnt_in, sclg);
    k_gemm<<<32768 / 128, 256, 0, stream>>>(agg, W2, b2, f1d, Wsv, sclg, outbuf, tbuf);
    k_pool<128, 64, true><<<NG, 128, 0, stream>>>(tbuf, bucket, cnt_in, bsv, src2, dst2,
                                                  scoreX, gate, perm_d, perm_c, src3, dst3);
    k_gather<<<NG * 64, 128, 0, stream>>>(outbuf, gate, perm_d, f2d);
    k_readout<<<2 * NG, 128, 0, stream>>>(outbuf, gate, perm_d, perm_c, 64, hg, hg_com, nullptr);

    // =================== stage 3 (N=16384, np=64, k=32) ====================
    k_agg_build<64><<<NG, 512, 0, stream>>>(f2d, src3, dst3, agg, bucket, cnt_in, sclg);
    k_gemm<<<16384 / 128, 256, 0, stream>>>(agg, W3, b3, f2d, Wsv, sclg, outbuf, tbuf);
    k_pool<64, 32, false><<<NG, 64, 0, stream>>>(tbuf, bucket, cnt_in, bsv, nullptr, nullptr,
                                                 scoreX, gate, perm_d, perm_c, nullptr, nullptr);
    k_readout<<<2 * NG, 128, 0, stream>>>(outbuf, gate, perm_d, perm_c, 32, hg, hg_com, o_hg3com);

    // =================== heads =============================================
    k_node_mlp<<<16384 / 16, 256, 0, stream>>>(outbuf, Wp0, bp0, Wp1, bp1, Wp2, bp2, o_nodepred);
    k_graph_mlp<<<128, 256, 0, stream>>>(hg, hg_com, Wg0, bg0, Wg1, bg1, Wg2, bg2, o_scores);
    k_smax_part<<<64, 256, 0, stream>>>(score1, pmax);
    k_smax_sum<<<64, 256, 0, stream>>>(score1, pmax, psum);
    k_smax_out<<<N1 / 256, 256, 0, stream>>>(score1, pmax, psum, o_nodescore);
}

// Round 10
// 390.462 us; speedup vs baseline: 1.5012x; 1.0080x over previous
//
#include <hip/hip_runtime.h>
#include <math.h>

#define NG    256          // graphs
#define D     128          // feature dim
#define EPG   4096         // edge capacity per graph (constant across stages)
#define NEDGE (NG*EPG)     // 1048576
#define CAP   48           // incoming-edge bucket capacity per node (P(deg>48) ~ 6e-11)
#define N1    65536        // stage-1 node count

typedef unsigned short u16;
typedef unsigned int   u32;

// ---------------------------------------------------------------------------
// Fused per-graph build + aggregate (unchanged from round 9).
template<int NPn>
__global__ __launch_bounds__(512) void k_agg_build(
    const float* __restrict__ x, const int* __restrict__ srcE, const int* __restrict__ dstE,
    float* __restrict__ agg, u16* __restrict__ bucket_g,
    int* __restrict__ cnt_in_g, float* __restrict__ sclg)
{
    constexpr int NCH = NPn / 16;         // float4 chunks per thread (16 at NPn=256)
    __shared__ float feat[NPn * 128];     // 128 KB at NPn=256
    __shared__ u16   bkt[NPn * CAP];      // 24 KB at NPn=256
    __shared__ int   cin[NPn];
    __shared__ int   cout[NPn];
    __shared__ float scll[NPn];
    const int g = ((blockIdx.x & 7) << 5) | (blockIdx.x >> 3);  // graph g on XCD g/32
    const int t = threadIdx.x;

    for (int i = t; i < NPn; i += 512) { cin[i] = 0; cout[i] = 0; }

    // ---- issue staging loads EARLY (raw features + this thread's 8 edges) --
    float4 fx[NCH];
    const float4* xsrc = (const float4*)(x + (size_t)g * NPn * 128);
#pragma unroll
    for (int c = 0; c < NCH; ++c) fx[c] = xsrc[c * 512 + t];
    int es[8], ed[8];
#pragma unroll
    for (int j = 0; j < 8; ++j) {
        es[j] = srcE[g * EPG + j * 512 + t];
        ed[j] = dstE[g * EPG + j * 512 + t];
    }
    __builtin_amdgcn_sched_barrier(0);    // keep the load issues above this point
    __syncthreads();

    // ---- pass A: count + bucket-fill via LDS atomics ----------------------
#pragma unroll
    for (int j = 0; j < 8; ++j) {
        int s = es[j];
        if (s >= 0) {
            int sl = s - g * NPn;
            int dl = ed[j] - g * NPn;
            atomicAdd(&cout[sl], 1);
            int pos = atomicAdd(&cin[dl], 1);
            if (pos < CAP) bkt[dl * CAP + pos] = (u16)sl;
        }
    }
    __syncthreads();

    // ---- pass B: scl + global dumps ---------------------------------------
    for (int i = t; i < NPn; i += 512) {
        cnt_in_g[g * NPn + i] = cin[i];
        float sc = rsqrtf((float)max(cout[i], 1));
        sclg[g * NPn + i] = sc;
        scll[i] = sc;
    }
    __syncthreads();

    // ---- write feat = fx * scl (scale-on-write) ---------------------------
#pragma unroll
    for (int c = 0; c < NCH; ++c) {
        int idx = c * 512 + t;
        float s = scll[idx >> 5];         // 32 float4 per row
        float4 v = fx[c];
        v.x *= s; v.y *= s; v.z *= s; v.w *= s;
        *(float4*)&feat[idx * 4] = v;
    }
    // dump bucket to global (coalesced u32 view) for k_pool
    {
        const int nw = NPn * CAP / 2;
        const u32* bw = (const u32*)bkt;
        u32* bg = (u32*)(bucket_g + (size_t)g * NPn * CAP);
        for (int i = t; i < nw; i += 512) bg[i] = bw[i];
    }
    __syncthreads();

    // ---- pass D: aggregate, 4-unrolled ------------------------------------
    const int w = t >> 6, l = t & 63;
    for (int n = w; n < NPn; n += 8) {
        int cnt = __builtin_amdgcn_readfirstlane(min(cin[n], CAP));
        int bv = (l < cnt) ? (int)bkt[n * CAP + l] : 0;
        float ax0 = 0.f, ay0 = 0.f, ax1 = 0.f, ay1 = 0.f;
        int i = 0;
        for (; i + 4 <= cnt; i += 4) {
            int s0 = __builtin_amdgcn_readlane(bv, i);
            int s1 = __builtin_amdgcn_readlane(bv, i + 1);
            int s2 = __builtin_amdgcn_readlane(bv, i + 2);
            int s3 = __builtin_amdgcn_readlane(bv, i + 3);
            float2 v0 = *(const float2*)&feat[s0 * 128 + 2 * l];
            float2 v1 = *(const float2*)&feat[s1 * 128 + 2 * l];
            float2 v2 = *(const float2*)&feat[s2 * 128 + 2 * l];
            float2 v3 = *(const float2*)&feat[s3 * 128 + 2 * l];
            ax0 += v0.x; ay0 += v0.y; ax0 += v1.x; ay0 += v1.y;
            ax1 += v2.x; ay1 += v2.y; ax1 += v3.x; ay1 += v3.y;
        }
        for (; i < cnt; ++i) {
            int s0 = __builtin_amdgcn_readlane(bv, i);
            float2 v0 = *(const float2*)&feat[s0 * 128 + 2 * l];
            ax0 += v0.x; ay0 += v0.y;
        }
        float sc = rsqrtf((float)max(cnt, 1));
        float ax = ax0 + ax1, ay = ay0 + ay1;
        *(float2*)&agg[((size_t)(g * NPn + n)) * D + 2 * l] = make_float2(ax * sc, ay * sc);
    }
}

// ---------------------------------------------------------------------------
// out = res + relu(agg @ W + b); epilogue also emits t[n] = dot(out[n],Ws)*scl[n].
// Retiled 64x128 per block, 128 threads, micro 8x8 (was 128x128/256thr):
// grid 4 blocks/CU (was 2), LDS 26 KB (part[] aliases At4 after last phase).
// Per-output k-order, epilogue order, Ws-dot chunk order unchanged -> bit-identical.
__global__ __launch_bounds__(128) void k_gemm(
    const float* __restrict__ A, const float* __restrict__ Wm,
    const float* __restrict__ bias, const float* __restrict__ res,
    const float* __restrict__ Wsv, const float* __restrict__ sclg,
    float* __restrict__ outp, float* __restrict__ tbuf)
{
    __shared__ float4 At4[16 * 33];   // [perm(r/4)][kl] rows of A; reused as part[] after
    __shared__ float4 Wt4[32 * 33];   // [perm(c/4)][kl]
    __shared__ float  Wsl[128];
    const int t  = threadIdx.x;
    const int tr = t >> 4;            // 0..7  : rows 8tr..8tr+7
    const int tc = t & 15;            // 0..15 : cols 8tc..8tc+7
    const int cb = tc * 8;
    const int lb = ((blockIdx.x & 7) * (gridDim.x >> 3)) + (blockIdx.x >> 3);
    const size_t r0 = (size_t)lb * 64;

    Wsl[t] = Wsv[t];

    float acc[8][8];
#pragma unroll
    for (int i = 0; i < 8; ++i)
#pragma unroll
        for (int j = 0; j < 8; ++j) acc[i][j] = 0.f;

    for (int ph = 0; ph < 4; ++ph) {
        __syncthreads();
        // stage A-quarter: 64 rows x 32 k (512 float4, coalesced)
#pragma unroll
        for (int s2 = 0; s2 < 4; ++s2) {
            int idx = t + 128 * s2;
            int r  = idx >> 3;        // 0..63
            int kc = idx & 7;         // 0..7
            float4 v = *(const float4*)&A[(r0 + r) * D + ph * 32 + kc * 4];
            int r4 = r >> 2, lane = r & 3;
            int prow = (r4 >> 1) | ((r4 & 1) << 3);   // 0..15
            float* base = (float*)&At4[prow * 33 + kc * 4];
            base[0  + lane] = v.x;
            base[4  + lane] = v.y;
            base[8  + lane] = v.z;
            base[12 + lane] = v.w;
        }
        // stage W-quarter: 32 k x 128 cols (1024 float4)
#pragma unroll
        for (int s2 = 0; s2 < 8; ++s2) {
            int idx = t + 128 * s2;
            int wr  = idx >> 5;       // 0..31 (k)
            int wc4 = idx & 31;       // col quad
            float4 v = *(const float4*)&Wm[(size_t)(ph * 32 + wr) * D + wc4 * 4];
            int pcol = (wc4 >> 1) | ((wc4 & 1) << 4);
            Wt4[pcol * 33 + wr] = v;
        }
        __syncthreads();
#pragma unroll 4
        for (int kl = 0; kl < 32; ++kl) {
            float4 a0 = At4[tr * 33 + kl];          // rows 8tr..8tr+3
            float4 a1 = At4[(tr + 8) * 33 + kl];    // rows 8tr+4..8tr+7
            float4 w0 = Wt4[tc * 33 + kl];
            float4 w1 = Wt4[(tc + 16) * 33 + kl];
            float av[8] = {a0.x, a0.y, a0.z, a0.w, a1.x, a1.y, a1.z, a1.w};
            float wv[8] = {w0.x, w0.y, w0.z, w0.w, w1.x, w1.y, w1.z, w1.w};
#pragma unroll
            for (int i = 0; i < 8; ++i)
#pragma unroll
                for (int j = 0; j < 8; ++j)
                    acc[i][j] += av[i] * wv[j];
        }
    }
    __syncthreads();
    float* part = (float*)At4;        // A-tile dead; reuse as part[64][17]
    float bv[8];
#pragma unroll
    for (int j = 0; j < 8; ++j) bv[j] = bias[cb + j];
#pragma unroll
    for (int i = 0; i < 8; ++i) {
        size_t row = r0 + tr * 8 + i;
        float4 rA = *(const float4*)&res[row * D + cb];
        float4 rB = *(const float4*)&res[row * D + cb + 4];
        float o0 = rA.x + fmaxf(acc[i][0] + bv[0], 0.f);
        float o1 = rA.y + fmaxf(acc[i][1] + bv[1], 0.f);
        float o2 = rA.z + fmaxf(acc[i][2] + bv[2], 0.f);
        float o3 = rA.w + fmaxf(acc[i][3] + bv[3], 0.f);
        float o4 = rB.x + fmaxf(acc[i][4] + bv[4], 0.f);
        float o5 = rB.y + fmaxf(acc[i][5] + bv[5], 0.f);
        float o6 = rB.z + fmaxf(acc[i][6] + bv[6], 0.f);
        float o7 = rB.w + fmaxf(acc[i][7] + bv[7], 0.f);
        *(float4*)&outp[row * D + cb]     = make_float4(o0, o1, o2, o3);
        *(float4*)&outp[row * D + cb + 4] = make_float4(o4, o5, o6, o7);
        float p = o0 * Wsl[cb + 0] + o1 * Wsl[cb + 1] + o2 * Wsl[cb + 2] + o3 * Wsl[cb + 3]
                + o4 * Wsl[cb + 4] + o5 * Wsl[cb + 5] + o6 * Wsl[cb + 6] + o7 * Wsl[cb + 7];
        part[(tr * 8 + i) * 17 + tc] = p;
    }
    __syncthreads();
    if (t < 64) {
        float s = 0.f;
#pragma unroll
        for (int j = 0; j < 16; ++j) s += part[t * 17 + j];
        size_t n = r0 + t;
        tbuf[n] = s * sclg[n];
    }
}

// ---------------------------------------------------------------------------
// Per-graph pooling (unchanged).
template<int NPn, int K, bool REMAP>
__global__ __launch_bounds__(NPn) void k_pool(
    const float* __restrict__ tbuf, const u16* __restrict__ bucket,
    const int* __restrict__ cnt_in, const float* __restrict__ bsv,
    const int* __restrict__ srcE, const int* __restrict__ dstE,
    float* __restrict__ score_out, float* __restrict__ gate_out,
    int* __restrict__ perm_dis, int* __restrict__ perm_com,
    int* __restrict__ src_next, int* __restrict__ dst_next)
{
    __shared__ float sc[NPn];
    __shared__ int   pf[NPn];
    __shared__ int   lid[NPn];
    const int g = ((blockIdx.x & 7) << 5) | (blockIdx.x >> 3);
    const int t = threadIdx.x;
    const int n = g * NPn + t;

    int cnt = cnt_in[n]; if (cnt > CAP) cnt = CAP;
    const u16* bk = bucket + (size_t)n * CAP;
    float a = 0.f;
    int i = 0;
    for (; i + 2 <= cnt; i += 2) {
        float v0 = tbuf[g * NPn + bk[i]];
        float v1 = tbuf[g * NPn + bk[i + 1]];
        a += v0; a += v1;
    }
    if (i < cnt) a += tbuf[g * NPn + bk[i]];
    float my = a * rsqrtf((float)max(cnt, 1)) + bsv[0];
    score_out[n] = my;
    gate_out[n]  = tanhf(my);
    sc[t] = my;
    __syncthreads();

    int rank = 0;
    for (int j = 0; j < NPn; ++j) {
        float v = sc[j];
        rank += (int)((v > my) || (v == my && j < t));
    }
    const int kept = (rank < K) ? 1 : 0;
    pf[t] = kept;
    __syncthreads();
    int val = kept;
    for (int off = 1; off < NPn; off <<= 1) {
        int add = (t >= off) ? pf[t - off] : 0;
        __syncthreads();
        val += add;
        pf[t] = val;
        __syncthreads();
    }
    int excl = val - kept;
    if (kept) { lid[t] = excl;  perm_dis[g * K + excl] = n; }
    else      { lid[t] = -1;    perm_com[g * (NPn - K) + (t - excl)] = n; }
    __syncthreads();

    if (REMAP) {
        for (int e = g * EPG + t; e < (g + 1) * EPG; e += NPn) {
            int s = srcE[e];
            int ns = -1, nd = -1;
            if (s >= 0) {
                int ls  = lid[s - g * NPn];
                int ld2 = lid[dstE[e] - g * NPn];
                if (ls >= 0 && ld2 >= 0) { ns = g * K + ls; nd = g * K + ld2; }
            }
            src_next[e] = ns;
            dst_next[e] = nd;
        }
    }
}

// ---------------------------------------------------------------------------
__global__ __launch_bounds__(128) void k_gather(
    const float* __restrict__ x, const float* __restrict__ gate,
    const int* __restrict__ perm, float* __restrict__ outf)
{
    int i = blockIdx.x, t = threadIdx.x;
    int old = perm[i];
    outf[(size_t)i * D + t] = x[(size_t)old * D + t] * gate[old];
}

__global__ __launch_bounds__(128) void k_readout(
    const float* __restrict__ x, const float* __restrict__ gate,
    const int* __restrict__ perm_dis, const int* __restrict__ perm_com,
    int kcnt, float* __restrict__ hg, float* __restrict__ hgc,
    float* __restrict__ copy_com)
{
    int b = blockIdx.x, t = threadIdx.x;
    int com = (b >= NG) ? 1 : 0;
    int g = com ? b - NG : b;
    const int* perm = (com ? perm_com : perm_dis) + (size_t)g * kcnt;
    float sm = 0.f, mx = -INFINITY;
    int r = 0;
    for (; r + 4 <= kcnt; r += 4) {   // 4 rows in flight
        int o0 = perm[r], o1 = perm[r + 1], o2 = perm[r + 2], o3 = perm[r + 3];
        float v0 = x[(size_t)o0 * D + t] * gate[o0];
        float v1 = x[(size_t)o1 * D + t] * gate[o1];
        float v2 = x[(size_t)o2 * D + t] * gate[o2];
        float v3 = x[(size_t)o3 * D + t] * gate[o3];
        sm += v0; mx = fmaxf(mx, v0);
        sm += v1; mx = fmaxf(mx, v1);
        sm += v2; mx = fmaxf(mx, v2);
        sm += v3; mx = fmaxf(mx, v3);
    }
    for (; r < kcnt; ++r) {
        int o0 = perm[r];
        float v = x[(size_t)o0 * D + t] * gate[o0];
        sm += v; mx = fmaxf(mx, v);
    }
    float mean = sm * (1.f / (float)kcnt);
    float* dstp = com ? hgc : hg;
    dstp[(size_t)g * 256 + t]       += mean;
    dstp[(size_t)g * 256 + 128 + t] += mx;
    if (com && copy_com) {
        copy_com[(size_t)g * 256 + t]       = mean;
        copy_com[(size_t)g * 256 + 128 + t] = mx;
    }
}

// ---------------------------------------------------------------------------
__global__ __launch_bounds__(256) void k_node_mlp(
    const float* __restrict__ X,
    const float* __restrict__ W0, const float* __restrict__ b0,
    const float* __restrict__ W1, const float* __restrict__ b1,
    const float* __restrict__ W2, const float* __restrict__ b2,
    float* __restrict__ outp)
{
    __shared__ float xs[16 * 132];
    __shared__ float w0[128 * 64];
    __shared__ float h0[16 * 65];
    __shared__ float w1[64 * 32];
    __shared__ float h1[16 * 33];
    __shared__ float w2[32 * 10];
    int t = threadIdx.x;
    int r0 = blockIdx.x * 16;
    for (int i = t; i < 128 * 64; i += 256) w0[i] = W0[i];
    for (int i = t; i < 64 * 32;  i += 256) w1[i] = W1[i];
    for (int i = t; i < 320;      i += 256) w2[i] = W2[i];
    for (int i = t; i < 16 * 128; i += 256)
        xs[(i >> 7) * 132 + (i & 127)] = X[(size_t)(r0 + (i >> 7)) * D + (i & 127)];
    __syncthreads();
    {
        int r = t >> 4, c = (t & 15) * 4;
        float a0 = b0[c], a1 = b0[c + 1], a2 = b0[c + 2], a3 = b0[c + 3];
        const float* xr = &xs[r * 132];
        for (int k = 0; k < 128; ++k) {
            float xv = xr[k];
            float4 w = *(const float4*)&w0[k * 64 + c];
            a0 += xv * w.x; a1 += xv * w.y; a2 += xv * w.z; a3 += xv * w.w;
        }
        float* hr = &h0[r * 65 + c];
        hr[0] = fmaxf(a0, 0.f); hr[1] = fmaxf(a1, 0.f); hr[2] = fmaxf(a2, 0.f); hr[3] = fmaxf(a3, 0.f);
    }
    __syncthreads();
    {
        int r = t >> 4, c = (t & 15) * 2;
        float a0 = b1[c], a1 = b1[c + 1];
        const float* hr = &h0[r * 65];
        for (int k = 0; k < 64; ++k) {
            float xv = hr[k];
            a0 += xv * w1[k * 32 + c];
            a1 += xv * w1[k * 32 + c + 1];
        }
        h1[r * 33 + c]     = fmaxf(a0, 0.f);
        h1[r * 33 + c + 1] = fmaxf(a1, 0.f);
    }
    __syncthreads();
    if (t < 160) {
        int r = t / 10, c = t % 10;
        float a = b2[c];
        const float* hr = &h1[r * 33];
        for (int k = 0; k < 32; ++k) a += hr[k] * w2[k * 10 + c];
        outp[(size_t)(r0 + r) * 10 + c] = a;
    }
}

// ---------------------------------------------------------------------------
// scores/scores_com MLP (unchanged from round 9 rework).
__global__ __launch_bounds__(256) void k_graph_mlp(
    const float* __restrict__ hg, const float* __restrict__ hgc,
    const float* __restrict__ Wg0, const float* __restrict__ bg0,
    const float* __restrict__ Wg1, const float* __restrict__ bg1,
    const float* __restrict__ Wg2, const float* __restrict__ bg2,
    float* __restrict__ outp)
{
    __shared__ float xs[4][260];
    __shared__ float h0[4][132];
    __shared__ float h1[4][68];
    const int t = threadIdx.x;
    const int row0 = blockIdx.x * 4;
    {   // stage 4 rows (256 float4, one per thread)
        int r = t >> 6, q = t & 63;
        int gr = row0 + r;
        const float* srcp = (gr < NG) ? &hg[(size_t)gr * 256] : &hgc[(size_t)(gr - NG) * 256];
        *(float4*)&xs[r][q * 4] = *(const float4*)&srcp[q * 4];
    }
    __syncthreads();
    {   // L0: 256 -> 128, relu; thread: col c, 2 rows
        int c = t & 127, rp = (t >> 7) * 2;
        float bb = bg0[c];
        float a0 = bb, a1 = bb;
        for (int k = 0; k < 256; ++k) {
            float w = Wg0[(size_t)k * 128 + c];
            a0 += xs[rp][k] * w;
            a1 += xs[rp + 1][k] * w;
        }
        h0[rp][c]     = fmaxf(a0, 0.f);
        h0[rp + 1][c] = fmaxf(a1, 0.f);
    }
    __syncthreads();
    {   // L1: 128 -> 64, relu
        int c = t & 63, r = t >> 6;
        float a = bg1[c];
        for (int k = 0; k < 128; ++k) a += h0[r][k] * Wg1[(size_t)k * 64 + c];
        h1[r][c] = fmaxf(a, 0.f);
    }
    __syncthreads();
    if (t < 40) {   // L2: 64 -> 10
        int r = t / 10, c = t % 10;
        float a = bg2[c];
        for (int k = 0; k < 64; ++k) a += h1[r][k] * Wg2[k * 10 + c];
        outp[(size_t)(row0 + r) * 10 + c] = a;
    }
}

// ---------------------------------------------------------------------------
__global__ __launch_bounds__(256) void k_smax_part(const float* __restrict__ sc, float* __restrict__ pmax) {
    __shared__ float red[256];
    int t = threadIdx.x;
    float m = -INFINITY;
    for (int i = blockIdx.x * 256 + t; i < N1; i += 64 * 256) m = fmaxf(m, sc[i]);
    red[t] = m; __syncthreads();
    for (int off = 128; off > 0; off >>= 1) {
        if (t < off) red[t] = fmaxf(red[t], red[t + off]);
        __syncthreads();
    }
    if (t == 0) pmax[blockIdx.x] = red[0];
}
__global__ __launch_bounds__(256) void k_smax_sum(const float* __restrict__ sc, const float* __restrict__ pmax,
                                                 float* __restrict__ psum) {
    __shared__ float red[256];
    int t = threadIdx.x;
    float gm = -INFINITY;
#pragma unroll
    for (int i = 0; i < 64; ++i) gm = fmaxf(gm, pmax[i]);
    float s = 0.f;
    for (int i = blockIdx.x * 256 + t; i < N1; i += 64 * 256) s += expf(sc[i] - gm);
    red[t] = s; __syncthreads();
    for (int off = 128; off > 0; off >>= 1) {
        if (t < off) red[t] += red[t + off];
        __syncthreads();
    }
    if (t == 0) psum[blockIdx.x] = red[0];
}
__global__ __launch_bounds__(256) void k_smax_out(const float* __restrict__ sc, const float* __restrict__ pmax,
                                                 const float* __restrict__ psum, float* __restrict__ outp) {
    int t = threadIdx.x;
    float gm = -INFINITY; float gs = 0.f;
#pragma unroll
    for (int i = 0; i < 64; ++i) { gm = fmaxf(gm, pmax[i]); gs += psum[i]; }
    int i = blockIdx.x * 256 + t;
    outp[i] = expf(sc[i] - gm) / gs;
}

// ---------------------------------------------------------------------------
extern "C" void kernel_launch(void* const* d_in, const int* in_sizes, int n_in,
                              void* d_out, int out_size, void* d_ws, size_t ws_size,
                              hipStream_t stream) {
    const float* feature = (const float*)d_in[0];
    const int*   src     = (const int*)d_in[1];
    const int*   dst     = (const int*)d_in[2];
    const float* W1  = (const float*)d_in[4];
    const float* b1  = (const float*)d_in[5];
    const float* W2  = (const float*)d_in[6];
    const float* b2  = (const float*)d_in[7];
    const float* W3  = (const float*)d_in[8];
    const float* b3  = (const float*)d_in[9];
    const float* Wsv = (const float*)d_in[10];
    const float* bsv = (const float*)d_in[11];
    const float* Wg0 = (const float*)d_in[12];
    const float* bg0 = (const float*)d_in[13];
    const float* Wg1 = (const float*)d_in[14];
    const float* bg1 = (const float*)d_in[15];
    const float* Wg2 = (const float*)d_in[16];
    const float* bg2 = (const float*)d_in[17];
    const float* Wp0 = (const float*)d_in[18];
    const float* bp0 = (const float*)d_in[19];
    const float* Wp1 = (const float*)d_in[20];
    const float* bp1 = (const float*)d_in[21];
    const float* Wp2 = (const float*)d_in[22];
    const float* bp2 = (const float*)d_in[23];

    float* out = (float*)d_out;
    float* o_scores    = out;            // [512][10]
    float* o_hg3com    = out + 5120;     // [256][256]
    float* o_nodepred  = out + 70656;    // [16384][10]
    float* o_nodescore = out + 234496;   // [65536]

    float* ws = (float*)d_ws;
    size_t off = 0;
    auto alloc_f = [&](size_t n) { float* p = ws + off; off += (n + 63) & ~(size_t)63; return p; };
    float* agg    = alloc_f(8388608);   // [65536][128]
    float* outbuf = alloc_f(8388608);
    float* f1d    = alloc_f(4194304);
    float* f2d    = alloc_f(2097152);
    u16*   bucket = (u16*)alloc_f(1572864);   // [65536][48] ushort
    int*   src2   = (int*)alloc_f(1048576);
    int*   dst2   = (int*)alloc_f(1048576);
    int*   src3   = (int*)alloc_f(1048576);
    int*   dst3   = (int*)alloc_f(1048576);
    int*   cnt_in = (int*)alloc_f(65536);
    float* sclg   = alloc_f(65536);
    float* tbuf   = alloc_f(65536);
    float* gate   = alloc_f(65536);
    float* score1 = alloc_f(65536);
    float* scoreX = alloc_f(65536);
    int*   perm_d = (int*)alloc_f(32768);
    int*   perm_c = (int*)alloc_f(32768);
    float* hg     = alloc_f(65536);
    float* hg_com = alloc_f(65536);
    float* pmax   = alloc_f(64);
    float* psum   = alloc_f(64);
    (void)ws_size; (void)in_sizes; (void)n_in; (void)out_size;

    hipMemsetAsync(hg, 0, 2 * 65536 * sizeof(float), stream);

    // =================== stage 1 (N=65536, np=256, k=128) ==================
    k_agg_build<256><<<NG, 512, 0, stream>>>(feature, src, dst, agg, bucket, cnt_in, sclg);
    k_gemm<<<65536 / 64, 128, 0, stream>>>(agg, W1, b1, feature, Wsv, sclg, outbuf, tbuf);
    k_pool<256, 128, true><<<NG, 256, 0, stream>>>(tbuf, bucket, cnt_in, bsv, src, dst,
                                                   score1, gate, perm_d, perm_c, src2, dst2);
    k_gather<<<NG * 128, 128, 0, stream>>>(outbuf, gate, perm_d, f1d);
    k_readout<<<2 * NG, 128, 0, stream>>>(outbuf, gate, perm_d, perm_c, 128, hg, hg_com, nullptr);

    // =================== stage 2 (N=32768, np=128, k=64) ===================
    k_agg_build<128><<<NG, 512, 0, stream>>>(f1d, src2, dst2, agg, bucket, cnt_in, sclg);
    k_gemm<<<32768 / 64, 128, 0, stream>>>(agg, W2, b2, f1d, Wsv, sclg, outbuf, tbuf);
    k_pool<128, 64, true><<<NG, 128, 0, stream>>>(tbuf, bucket, cnt_in, bsv, src2, dst2,
                                                  scoreX, gate, perm_d, perm_c, src3, dst3);
    k_gather<<<NG * 64, 128, 0, stream>>>(outbuf, gate, perm_d, f2d);
    k_readout<<<2 * NG, 128, 0, stream>>>(outbuf, gate, perm_d, perm_c, 64, hg, hg_com, nullptr);

    // =================== stage 3 (N=16384, np=64, k=32) ====================
    k_agg_build<64><<<NG, 512, 0, stream>>>(f2d, src3, dst3, agg, bucket, cnt_in, sclg);
    k_gemm<<<16384 / 64, 128, 0, stream>>>(agg, W3, b3, f2d, Wsv, sclg, outbuf, tbuf);
    k_pool<64, 32, false><<<NG, 64, 0, stream>>>(tbuf, bucket, cnt_in, bsv, nullptr, nullptr,
                                                 scoreX, gate, perm_d, perm_c, nullptr, nullptr);
    k_readout<<<2 * NG, 128, 0, stream>>>(outbuf, gate, perm_d, perm_c, 32, hg, hg_com, o_hg3com);

    // =================== heads =============================================
    k_node_mlp<<<16384 / 16, 256, 0, stream>>>(outbuf, Wp0, bp0, Wp1, bp1, Wp2, bp2, o_nodepred);
    k_graph_mlp<<<128, 256, 0, stream>>>(hg, hg_com, Wg0, bg0, Wg1, bg1, Wg2, bg2, o_scores);
    k_smax_part<<<64, 256, 0, stream>>>(score1, pmax);
    k_smax_sum<<<64, 256, 0, stream>>>(score1, pmax, psum);
    k_smax_out<<<N1 / 256, 256, 0, stream>>>(score1, pmax, psum, o_nodescore);
}

// Round 11
// 375.032 us; speedup vs baseline: 1.5630x; 1.0411x over previous
//
#include <hip/hip_runtime.h>
#include <math.h>

#define NG    256          // graphs
#define D     128          // feature dim
#define EPG   4096         // edge capacity per graph (constant across stages)
#define NEDGE (NG*EPG)     // 1048576
#define CAP   48           // incoming-edge bucket capacity per node (P(deg>48) ~ 6e-11)
#define N1    65536        // stage-1 node count

typedef unsigned short u16;
typedef unsigned int   u32;

// ---------------------------------------------------------------------------
// Fused per-graph build + aggregate. Now 1024 threads/block: LDS still caps at
// 1 block/CU, but 16 waves (4/SIMD) instead of 8 doubles latency hiding in
// every phase. Same value-producing expressions as the passing round.
template<int NPn>
__global__ __launch_bounds__(1024) void k_agg_build(
    const float* __restrict__ x, const int* __restrict__ srcE, const int* __restrict__ dstE,
    float* __restrict__ agg, u16* __restrict__ bucket_g,
    int* __restrict__ cnt_in_g, float* __restrict__ sclg)
{
    constexpr int NCH = NPn / 32;         // float4 chunks per thread (8 at NPn=256)
    __shared__ float feat[NPn * 128];     // 128 KB at NPn=256
    __shared__ u16   bkt[NPn * CAP];      // 24 KB at NPn=256
    __shared__ int   cin[NPn];
    __shared__ int   cout[NPn];
    __shared__ float scll[NPn];
    const int g = ((blockIdx.x & 7) << 5) | (blockIdx.x >> 3);  // graph g on XCD g/32
    const int t = threadIdx.x;

    if (t < NPn) { cin[t] = 0; cout[t] = 0; }

    // ---- issue staging loads EARLY (raw features + this thread's 4 edges) --
    float4 fx[NCH];
    const float4* xsrc = (const float4*)(x + (size_t)g * NPn * 128);
#pragma unroll
    for (int c = 0; c < NCH; ++c) fx[c] = xsrc[c * 1024 + t];
    int es[4], ed[4];
#pragma unroll
    for (int j = 0; j < 4; ++j) {
        es[j] = srcE[g * EPG + j * 1024 + t];
        ed[j] = dstE[g * EPG + j * 1024 + t];
    }
    __builtin_amdgcn_sched_barrier(0);    // keep the load issues above this point
    __syncthreads();

    // ---- pass A: count + bucket-fill via LDS atomics ----------------------
#pragma unroll
    for (int j = 0; j < 4; ++j) {
        int s = es[j];
        if (s >= 0) {
            int sl = s - g * NPn;
            int dl = ed[j] - g * NPn;
            atomicAdd(&cout[sl], 1);
            int pos = atomicAdd(&cin[dl], 1);
            if (pos < CAP) bkt[dl * CAP + pos] = (u16)sl;
        }
    }
    __syncthreads();

    // ---- pass B: scl + global dumps ---------------------------------------
    if (t < NPn) {
        cnt_in_g[g * NPn + t] = cin[t];
        float sc = rsqrtf((float)max(cout[t], 1));
        sclg[g * NPn + t] = sc;
        scll[t] = sc;
    }
    __syncthreads();

    // ---- write feat = fx * scl (scale-on-write) ---------------------------
#pragma unroll
    for (int c = 0; c < NCH; ++c) {
        int idx = c * 1024 + t;
        float s = scll[idx >> 5];         // 32 float4 per row
        float4 v = fx[c];
        v.x *= s; v.y *= s; v.z *= s; v.w *= s;
        *(float4*)&feat[idx * 4] = v;
    }
    // dump bucket to global (coalesced u32 view) for k_pool
    {
        const int nw = NPn * CAP / 2;
        const u32* bw = (const u32*)bkt;
        u32* bg = (u32*)(bucket_g + (size_t)g * NPn * CAP);
        for (int i = t; i < nw; i += 1024) bg[i] = bw[i];
    }
    __syncthreads();

    // ---- pass D: aggregate, 4-unrolled, 16 waves --------------------------
    const int w = t >> 6, l = t & 63;
    for (int n = w; n < NPn; n += 16) {
        int cnt = __builtin_amdgcn_readfirstlane(min(cin[n], CAP));
        int bv = (l < cnt) ? (int)bkt[n * CAP + l] : 0;
        float ax0 = 0.f, ay0 = 0.f, ax1 = 0.f, ay1 = 0.f;
        int i = 0;
        for (; i + 4 <= cnt; i += 4) {
            int s0 = __builtin_amdgcn_readlane(bv, i);
            int s1 = __builtin_amdgcn_readlane(bv, i + 1);
            int s2 = __builtin_amdgcn_readlane(bv, i + 2);
            int s3 = __builtin_amdgcn_readlane(bv, i + 3);
            float2 v0 = *(const float2*)&feat[s0 * 128 + 2 * l];
            float2 v1 = *(const float2*)&feat[s1 * 128 + 2 * l];
            float2 v2 = *(const float2*)&feat[s2 * 128 + 2 * l];
            float2 v3 = *(const float2*)&feat[s3 * 128 + 2 * l];
            ax0 += v0.x; ay0 += v0.y; ax0 += v1.x; ay0 += v1.y;
            ax1 += v2.x; ay1 += v2.y; ax1 += v3.x; ay1 += v3.y;
        }
        for (; i < cnt; ++i) {
            int s0 = __builtin_amdgcn_readlane(bv, i);
            float2 v0 = *(const float2*)&feat[s0 * 128 + 2 * l];
            ax0 += v0.x; ay0 += v0.y;
        }
        float sc = rsqrtf((float)max(cnt, 1));
        float ax = ax0 + ax1, ay = ay0 + ay1;
        *(float2*)&agg[((size_t)(g * NPn + n)) * D + 2 * l] = make_float2(ax * sc, ay * sc);
    }
}

// ---------------------------------------------------------------------------
// out = res + relu(agg @ W + b); epilogue also emits t[n] = dot(out[n],Ws)*scl[n].
// 64x128 per block, 128 threads, micro 8x8 (unchanged from round 10).
__global__ __launch_bounds__(128) void k_gemm(
    const float* __restrict__ A, const float* __restrict__ Wm,
    const float* __restrict__ bias, const float* __restrict__ res,
    const float* __restrict__ Wsv, const float* __restrict__ sclg,
    float* __restrict__ outp, float* __restrict__ tbuf)
{
    __shared__ float4 At4[16 * 33];   // [perm(r/4)][kl] rows of A; reused as part[] after
    __shared__ float4 Wt4[32 * 33];   // [perm(c/4)][kl]
    __shared__ float  Wsl[128];
    const int t  = threadIdx.x;
    const int tr = t >> 4;            // 0..7  : rows 8tr..8tr+7
    const int tc = t & 15;            // 0..15 : cols 8tc..8tc+7
    const int cb = tc * 8;
    const int lb = ((blockIdx.x & 7) * (gridDim.x >> 3)) + (blockIdx.x >> 3);
    const size_t r0 = (size_t)lb * 64;

    Wsl[t] = Wsv[t];

    float acc[8][8];
#pragma unroll
    for (int i = 0; i < 8; ++i)
#pragma unroll
        for (int j = 0; j < 8; ++j) acc[i][j] = 0.f;

    for (int ph = 0; ph < 4; ++ph) {
        __syncthreads();
#pragma unroll
        for (int s2 = 0; s2 < 4; ++s2) {
            int idx = t + 128 * s2;
            int r  = idx >> 3;        // 0..63
            int kc = idx & 7;         // 0..7
            float4 v = *(const float4*)&A[(r0 + r) * D + ph * 32 + kc * 4];
            int r4 = r >> 2, lane = r & 3;
            int prow = (r4 >> 1) | ((r4 & 1) << 3);   // 0..15
            float* base = (float*)&At4[prow * 33 + kc * 4];
            base[0  + lane] = v.x;
            base[4  + lane] = v.y;
            base[8  + lane] = v.z;
            base[12 + lane] = v.w;
        }
#pragma unroll
        for (int s2 = 0; s2 < 8; ++s2) {
            int idx = t + 128 * s2;
            int wr  = idx >> 5;       // 0..31 (k)
            int wc4 = idx & 31;       // col quad
            float4 v = *(const float4*)&Wm[(size_t)(ph * 32 + wr) * D + wc4 * 4];
            int pcol = (wc4 >> 1) | ((wc4 & 1) << 4);
            Wt4[pcol * 33 + wr] = v;
        }
        __syncthreads();
#pragma unroll 4
        for (int kl = 0; kl < 32; ++kl) {
            float4 a0 = At4[tr * 33 + kl];
            float4 a1 = At4[(tr + 8) * 33 + kl];
            float4 w0 = Wt4[tc * 33 + kl];
            float4 w1 = Wt4[(tc + 16) * 33 + kl];
            float av[8] = {a0.x, a0.y, a0.z, a0.w, a1.x, a1.y, a1.z, a1.w};
            float wv[8] = {w0.x, w0.y, w0.z, w0.w, w1.x, w1.y, w1.z, w1.w};
#pragma unroll
            for (int i = 0; i < 8; ++i)
#pragma unroll
                for (int j = 0; j < 8; ++j)
                    acc[i][j] += av[i] * wv[j];
        }
    }
    __syncthreads();
    float* part = (float*)At4;        // A-tile dead; reuse as part[64][17]
    float bv[8];
#pragma unroll
    for (int j = 0; j < 8; ++j) bv[j] = bias[cb + j];
#pragma unroll
    for (int i = 0; i < 8; ++i) {
        size_t row = r0 + tr * 8 + i;
        float4 rA = *(const float4*)&res[row * D + cb];
        float4 rB = *(const float4*)&res[row * D + cb + 4];
        float o0 = rA.x + fmaxf(acc[i][0] + bv[0], 0.f);
        float o1 = rA.y + fmaxf(acc[i][1] + bv[1], 0.f);
        float o2 = rA.z + fmaxf(acc[i][2] + bv[2], 0.f);
        float o3 = rA.w + fmaxf(acc[i][3] + bv[3], 0.f);
        float o4 = rB.x + fmaxf(acc[i][4] + bv[4], 0.f);
        float o5 = rB.y + fmaxf(acc[i][5] + bv[5], 0.f);
        float o6 = rB.z + fmaxf(acc[i][6] + bv[6], 0.f);
        float o7 = rB.w + fmaxf(acc[i][7] + bv[7], 0.f);
        *(float4*)&outp[row * D + cb]     = make_float4(o0, o1, o2, o3);
        *(float4*)&outp[row * D + cb + 4] = make_float4(o4, o5, o6, o7);
        float p = o0 * Wsl[cb + 0] + o1 * Wsl[cb + 1] + o2 * Wsl[cb + 2] + o3 * Wsl[cb + 3]
                + o4 * Wsl[cb + 4] + o5 * Wsl[cb + 5] + o6 * Wsl[cb + 6] + o7 * Wsl[cb + 7];
        part[(tr * 8 + i) * 17 + tc] = p;
    }
    __syncthreads();
    if (t < 64) {
        float s = 0.f;
#pragma unroll
        for (int j = 0; j < 16; ++j) s += part[t * 17 + j];
        size_t n = r0 + t;
        tbuf[n] = s * sclg[n];
    }
}

// ---------------------------------------------------------------------------
// Per-graph pooling (unchanged).
template<int NPn, int K, bool REMAP>
__global__ __launch_bounds__(NPn) void k_pool(
    const float* __restrict__ tbuf, const u16* __restrict__ bucket,
    const int* __restrict__ cnt_in, const float* __restrict__ bsv,
    const int* __restrict__ srcE, const int* __restrict__ dstE,
    float* __restrict__ score_out, float* __restrict__ gate_out,
    int* __restrict__ perm_dis, int* __restrict__ perm_com,
    int* __restrict__ src_next, int* __restrict__ dst_next)
{
    __shared__ float sc[NPn];
    __shared__ int   pf[NPn];
    __shared__ int   lid[NPn];
    const int g = ((blockIdx.x & 7) << 5) | (blockIdx.x >> 3);
    const int t = threadIdx.x;
    const int n = g * NPn + t;

    int cnt = cnt_in[n]; if (cnt > CAP) cnt = CAP;
    const u16* bk = bucket + (size_t)n * CAP;
    float a = 0.f;
    int i = 0;
    for (; i + 2 <= cnt; i += 2) {
        float v0 = tbuf[g * NPn + bk[i]];
        float v1 = tbuf[g * NPn + bk[i + 1]];
        a += v0; a += v1;
    }
    if (i < cnt) a += tbuf[g * NPn + bk[i]];
    float my = a * rsqrtf((float)max(cnt, 1)) + bsv[0];
    score_out[n] = my;
    gate_out[n]  = tanhf(my);
    sc[t] = my;
    __syncthreads();

    int rank = 0;
    for (int j = 0; j < NPn; ++j) {
        float v = sc[j];
        rank += (int)((v > my) || (v == my && j < t));
    }
    const int kept = (rank < K) ? 1 : 0;
    pf[t] = kept;
    __syncthreads();
    int val = kept;
    for (int off = 1; off < NPn; off <<= 1) {
        int add = (t >= off) ? pf[t - off] : 0;
        __syncthreads();
        val += add;
        pf[t] = val;
        __syncthreads();
    }
    int excl = val - kept;
    if (kept) { lid[t] = excl;  perm_dis[g * K + excl] = n; }
    else      { lid[t] = -1;    perm_com[g * (NPn - K) + (t - excl)] = n; }
    __syncthreads();

    if (REMAP) {
        for (int e = g * EPG + t; e < (g + 1) * EPG; e += NPn) {
            int s = srcE[e];
            int ns = -1, nd = -1;
            if (s >= 0) {
                int ls  = lid[s - g * NPn];
                int ld2 = lid[dstE[e] - g * NPn];
                if (ls >= 0 && ld2 >= 0) { ns = g * K + ls; nd = g * K + ld2; }
            }
            src_next[e] = ns;
            dst_next[e] = nd;
        }
    }
}

// ---------------------------------------------------------------------------
// Fused gather + readout: dis blocks (b<NG) also write the gated features
// (f1d/f2d) — same product v = x[perm]·gate as the old k_gather, same loop
// order for mean/max -> identical values, 2 fewer dispatches, no re-read.
__global__ __launch_bounds__(128) void k_readout(
    const float* __restrict__ x, const float* __restrict__ gate,
    const int* __restrict__ perm_dis, const int* __restrict__ perm_com,
    int kcnt, float* __restrict__ hg, float* __restrict__ hgc,
    float* __restrict__ copy_com, float* __restrict__ outf)
{
    int b = blockIdx.x, t = threadIdx.x;
    int com = (b >= NG) ? 1 : 0;
    int g = com ? b - NG : b;
    const int* perm = (com ? perm_com : perm_dis) + (size_t)g * kcnt;
    float* of = (com || !outf) ? nullptr : outf + (size_t)g * kcnt * D;
    float sm = 0.f, mx = -INFINITY;
    int r = 0;
    for (; r + 4 <= kcnt; r += 4) {   // 4 rows in flight
        int o0 = perm[r], o1 = perm[r + 1], o2 = perm[r + 2], o3 = perm[r + 3];
        float v0 = x[(size_t)o0 * D + t] * gate[o0];
        float v1 = x[(size_t)o1 * D + t] * gate[o1];
        float v2 = x[(size_t)o2 * D + t] * gate[o2];
        float v3 = x[(size_t)o3 * D + t] * gate[o3];
        if (of) {
            of[(size_t)(r + 0) * D + t] = v0;
            of[(size_t)(r + 1) * D + t] = v1;
            of[(size_t)(r + 2) * D + t] = v2;
            of[(size_t)(r + 3) * D + t] = v3;
        }
        sm += v0; mx = fmaxf(mx, v0);
        sm += v1; mx = fmaxf(mx, v1);
        sm += v2; mx = fmaxf(mx, v2);
        sm += v3; mx = fmaxf(mx, v3);
    }
    for (; r < kcnt; ++r) {
        int o0 = perm[r];
        float v = x[(size_t)o0 * D + t] * gate[o0];
        if (of) of[(size_t)r * D + t] = v;
        sm += v; mx = fmaxf(mx, v);
    }
    float mean = sm * (1.f / (float)kcnt);
    float* dstp = com ? hgc : hg;
    dstp[(size_t)g * 256 + t]       += mean;
    dstp[(size_t)g * 256 + 128 + t] += mx;
    if (com && copy_com) {
        copy_com[(size_t)g * 256 + t]       = mean;
        copy_com[(size_t)g * 256 + 128 + t] = mx;
    }
}

// ---------------------------------------------------------------------------
__global__ __launch_bounds__(256) void k_node_mlp(
    const float* __restrict__ X,
    const float* __restrict__ W0, const float* __restrict__ b0,
    const float* __restrict__ W1, const float* __restrict__ b1,
    const float* __restrict__ W2, const float* __restrict__ b2,
    float* __restrict__ outp)
{
    __shared__ float xs[16 * 132];
    __shared__ float w0[128 * 64];
    __shared__ float h0[16 * 65];
    __shared__ float w1[64 * 32];
    __shared__ float h1[16 * 33];
    __shared__ float w2[32 * 10];
    int t = threadIdx.x;
    int r0 = blockIdx.x * 16;
    for (int i = t; i < 128 * 64; i += 256) w0[i] = W0[i];
    for (int i = t; i < 64 * 32;  i += 256) w1[i] = W1[i];
    for (int i = t; i < 320;      i += 256) w2[i] = W2[i];
    for (int i = t; i < 16 * 128; i += 256)
        xs[(i >> 7) * 132 + (i & 127)] = X[(size_t)(r0 + (i >> 7)) * D + (i & 127)];
    __syncthreads();
    {
        int r = t >> 4, c = (t & 15) * 4;
        float a0 = b0[c], a1 = b0[c + 1], a2 = b0[c + 2], a3 = b0[c + 3];
        const float* xr = &xs[r * 132];
        for (int k = 0; k < 128; ++k) {
            float xv = xr[k];
            float4 w = *(const float4*)&w0[k * 64 + c];
            a0 += xv * w.x; a1 += xv * w.y; a2 += xv * w.z; a3 += xv * w.w;
        }
        float* hr = &h0[r * 65 + c];
        hr[0] = fmaxf(a0, 0.f); hr[1] = fmaxf(a1, 0.f); hr[2] = fmaxf(a2, 0.f); hr[3] = fmaxf(a3, 0.f);
    }
    __syncthreads();
    {
        int r = t >> 4, c = (t & 15) * 2;
        float a0 = b1[c], a1 = b1[c + 1];
        const float* hr = &h0[r * 65];
        for (int k = 0; k < 64; ++k) {
            float xv = hr[k];
            a0 += xv * w1[k * 32 + c];
            a1 += xv * w1[k * 32 + c + 1];
        }
        h1[r * 33 + c]     = fmaxf(a0, 0.f);
        h1[r * 33 + c + 1] = fmaxf(a1, 0.f);
    }
    __syncthreads();
    if (t < 160) {
        int r = t / 10, c = t % 10;
        float a = b2[c];
        const float* hr = &h1[r * 33];
        for (int k = 0; k < 32; ++k) a += hr[k] * w2[k * 10 + c];
        outp[(size_t)(r0 + r) * 10 + c] = a;
    }
}

// ---------------------------------------------------------------------------
// scores/scores_com MLP (unchanged).
__global__ __launch_bounds__(256) void k_graph_mlp(
    const float* __restrict__ hg, const float* __restrict__ hgc,
    const float* __restrict__ Wg0, const float* __restrict__ bg0,
    const float* __restrict__ Wg1, const float* __restrict__ bg1,
    const float* __restrict__ Wg2, const float* __restrict__ bg2,
    float* __restrict__ outp)
{
    __shared__ float xs[4][260];
    __shared__ float h0[4][132];
    __shared__ float h1[4][68];
    const int t = threadIdx.x;
    const int row0 = blockIdx.x * 4;
    {   // stage 4 rows (256 float4, one per thread)
        int r = t >> 6, q = t & 63;
        int gr = row0 + r;
        const float* srcp = (gr < NG) ? &hg[(size_t)gr * 256] : &hgc[(size_t)(gr - NG) * 256];
        *(float4*)&xs[r][q * 4] = *(const float4*)&srcp[q * 4];
    }
    __syncthreads();
    {   // L0: 256 -> 128, relu; thread: col c, 2 rows
        int c = t & 127, rp = (t >> 7) * 2;
        float bb = bg0[c];
        float a0 = bb, a1 = bb;
        for (int k = 0; k < 256; ++k) {
            float w = Wg0[(size_t)k * 128 + c];
            a0 += xs[rp][k] * w;
            a1 += xs[rp + 1][k] * w;
        }
        h0[rp][c]     = fmaxf(a0, 0.f);
        h0[rp + 1][c] = fmaxf(a1, 0.f);
    }
    __syncthreads();
    {   // L1: 128 -> 64, relu
        int c = t & 63, r = t >> 6;
        float a = bg1[c];
        for (int k = 0; k < 128; ++k) a += h0[r][k] * Wg1[(size_t)k * 64 + c];
        h1[r][c] = fmaxf(a, 0.f);
    }
    __syncthreads();
    if (t < 40) {   // L2: 64 -> 10
        int r = t / 10, c = t % 10;
        float a = bg2[c];
        for (int k = 0; k < 64; ++k) a += h1[r][k] * Wg2[k * 10 + c];
        outp[(size_t)(row0 + r) * 10 + c] = a;
    }
}

// ---------------------------------------------------------------------------
__global__ __launch_bounds__(256) void k_smax_part(const float* __restrict__ sc, float* __restrict__ pmax) {
    __shared__ float red[256];
    int t = threadIdx.x;
    float m = -INFINITY;
    for (int i = blockIdx.x * 256 + t; i < N1; i += 64 * 256) m = fmaxf(m, sc[i]);
    red[t] = m; __syncthreads();
    for (int off = 128; off > 0; off >>= 1) {
        if (t < off) red[t] = fmaxf(red[t], red[t + off]);
        __syncthreads();
    }
    if (t == 0) pmax[blockIdx.x] = red[0];
}
__global__ __launch_bounds__(256) void k_smax_sum(const float* __restrict__ sc, const float* __restrict__ pmax,
                                                 float* __restrict__ psum) {
    __shared__ float red[256];
    int t = threadIdx.x;
    float gm = -INFINITY;
#pragma unroll
    for (int i = 0; i < 64; ++i) gm = fmaxf(gm, pmax[i]);
    float s = 0.f;
    for (int i = blockIdx.x * 256 + t; i < N1; i += 64 * 256) s += expf(sc[i] - gm);
    red[t] = s; __syncthreads();
    for (int off = 128; off > 0; off >>= 1) {
        if (t < off) red[t] += red[t + off];
        __syncthreads();
    }
    if (t == 0) psum[blockIdx.x] = red[0];
}
__global__ __launch_bounds__(256) void k_smax_out(const float* __restrict__ sc, const float* __restrict__ pmax,
                                                 const float* __restrict__ psum, float* __restrict__ outp) {
    int t = threadIdx.x;
    float gm = -INFINITY; float gs = 0.f;
#pragma unroll
    for (int i = 0; i < 64; ++i) { gm = fmaxf(gm, pmax[i]); gs += psum[i]; }
    int i = blockIdx.x * 256 + t;
    outp[i] = expf(sc[i] - gm) / gs;
}

// ---------------------------------------------------------------------------
extern "C" void kernel_launch(void* const* d_in, const int* in_sizes, int n_in,
                              void* d_out, int out_size, void* d_ws, size_t ws_size,
                              hipStream_t stream) {
    const float* feature = (const float*)d_in[0];
    const int*   src     = (const int*)d_in[1];
    const int*   dst     = (const int*)d_in[2];
    const float* W1  = (const float*)d_in[4];
    const float* b1  = (const float*)d_in[5];
    const float* W2  = (const float*)d_in[6];
    const float* b2  = (const float*)d_in[7];
    const float* W3  = (const float*)d_in[8];
    const float* b3  = (const float*)d_in[9];
    const float* Wsv = (const float*)d_in[10];
    const float* bsv = (const float*)d_in[11];
    const float* Wg0 = (const float*)d_in[12];
    const float* bg0 = (const float*)d_in[13];
    const float* Wg1 = (const float*)d_in[14];
    const float* bg1 = (const float*)d_in[15];
    const float* Wg2 = (const float*)d_in[16];
    const float* bg2 = (const float*)d_in[17];
    const float* Wp0 = (const float*)d_in[18];
    const float* bp0 = (const float*)d_in[19];
    const float* Wp1 = (const float*)d_in[20];
    const float* bp1 = (const float*)d_in[21];
    const float* Wp2 = (const float*)d_in[22];
    const float* bp2 = (const float*)d_in[23];

    float* out = (float*)d_out;
    float* o_scores    = out;            // [512][10]
    float* o_hg3com    = out + 5120;     // [256][256]
    float* o_nodepred  = out + 70656;    // [16384][10]
    float* o_nodescore = out + 234496;   // [65536]

    float* ws = (float*)d_ws;
    size_t off = 0;
    auto alloc_f = [&](size_t n) { float* p = ws + off; off += (n + 63) & ~(size_t)63; return p; };
    float* agg    = alloc_f(8388608);   // [65536][128]
    float* outbuf = alloc_f(8388608);
    float* f1d    = alloc_f(4194304);
    float* f2d    = alloc_f(2097152);
    u16*   bucket = (u16*)alloc_f(1572864);   // [65536][48] ushort
    int*   src2   = (int*)alloc_f(1048576);
    int*   dst2   = (int*)alloc_f(1048576);
    int*   src3   = (int*)alloc_f(1048576);
    int*   dst3   = (int*)alloc_f(1048576);
    int*   cnt_in = (int*)alloc_f(65536);
    float* sclg   = alloc_f(65536);
    float* tbuf   = alloc_f(65536);
    float* gate   = alloc_f(65536);
    float* score1 = alloc_f(65536);
    float* scoreX = alloc_f(65536);
    int*   perm_d = (int*)alloc_f(32768);
    int*   perm_c = (int*)alloc_f(32768);
    float* hg     = alloc_f(65536);
    float* hg_com = alloc_f(65536);
    float* pmax   = alloc_f(64);
    float* psum   = alloc_f(64);
    (void)ws_size; (void)in_sizes; (void)n_in; (void)out_size;

    hipMemsetAsync(hg, 0, 2 * 65536 * sizeof(float), stream);

    // =================== stage 1 (N=65536, np=256, k=128) ==================
    k_agg_build<256><<<NG, 1024, 0, stream>>>(feature, src, dst, agg, bucket, cnt_in, sclg);
    k_gemm<<<65536 / 64, 128, 0, stream>>>(agg, W1, b1, feature, Wsv, sclg, outbuf, tbuf);
    k_pool<256, 128, true><<<NG, 256, 0, stream>>>(tbuf, bucket, cnt_in, bsv, src, dst,
                                                   score1, gate, perm_d, perm_c, src2, dst2);
    k_readout<<<2 * NG, 128, 0, stream>>>(outbuf, gate, perm_d, perm_c, 128, hg, hg_com, nullptr, f1d);

    // =================== stage 2 (N=32768, np=128, k=64) ===================
    k_agg_build<128><<<NG, 1024, 0, stream>>>(f1d, src2, dst2, agg, bucket, cnt_in, sclg);
    k_gemm<<<32768 / 64, 128, 0, stream>>>(agg, W2, b2, f1d, Wsv, sclg, outbuf, tbuf);
    k_pool<128, 64, true><<<NG, 128, 0, stream>>>(tbuf, bucket, cnt_in, bsv, src2, dst2,
                                                  scoreX, gate, perm_d, perm_c, src3, dst3);
    k_readout<<<2 * NG, 128, 0, stream>>>(outbuf, gate, perm_d, perm_c, 64, hg, hg_com, nullptr, f2d);

    // =================== stage 3 (N=16384, np=64, k=32) ====================
    k_agg_build<64><<<NG, 1024, 0, stream>>>(f2d, src3, dst3, agg, bucket, cnt_in, sclg);
    k_gemm<<<16384 / 64, 128, 0, stream>>>(agg, W3, b3, f2d, Wsv, sclg, outbuf, tbuf);
    k_pool<64, 32, false><<<NG, 64, 0, stream>>>(tbuf, bucket, cnt_in, bsv, nullptr, nullptr,
                                                 scoreX, gate, perm_d, perm_c, nullptr, nullptr);
    k_readout<<<2 * NG, 128, 0, stream>>>(outbuf, gate, perm_d, perm_c, 32, hg, hg_com, o_hg3com, nullptr);

    // =================== heads =============================================
    k_node_mlp<<<16384 / 16, 256, 0, stream>>>(outbuf, Wp0, bp0, Wp1, bp1, Wp2, bp2, o_nodepred);
    k_graph_mlp<<<128, 256, 0, stream>>>(hg, hg_com, Wg0, bg0, Wg1, bg1, Wg2, bg2, o_scores);
    k_smax_part<<<64, 256, 0, stream>>>(score1, pmax);
    k_smax_sum<<<64, 256, 0, stream>>>(score1, pmax, psum);
    k_smax_out<<<N1 / 256, 256, 0, stream>>>(score1, pmax, psum, o_nodescore);
}